// Round 1
// baseline (408.296 us; speedup 1.0000x reference)
//
#include <hip/hip_runtime.h>

#define BATCH 16
#define CIN   256
#define NSP   4096
#define HID   512

typedef short v8s __attribute__((ext_vector_type(8)));
typedef float v4f __attribute__((ext_vector_type(4)));

__device__ __forceinline__ unsigned short f2bf(float f) {
    union { float f; unsigned u; } a; a.f = f;
    unsigned r = a.u + 0x7fffu + ((a.u >> 16) & 1u);
    return (unsigned short)(r >> 16);
}
__device__ __forceinline__ float bf2f(unsigned short s) {
    union { unsigned u; float f; } a; a.u = ((unsigned)s) << 16;
    return a.f;
}

// ---------------- K1: qkv = w_qkv(1536x256) @ x(256x4096) per batch ----------------
// q rows (o<512) written transposed qT[b][n][o] bf16; k,v rows written kv[b][o-512][n] bf16.
__global__ __launch_bounds__(256) void k_qkv(const float* __restrict__ x,
                                             const float* __restrict__ wq,
                                             unsigned short* __restrict__ qT,
                                             unsigned short* __restrict__ kv) {
    __shared__ unsigned short As[128 * 40];   // [m=o][k=c], stride 40
    __shared__ unsigned short Bs[128 * 40];   // [n][k=c],   stride 40
    const int t = threadIdx.x;
    const int bm = blockIdx.x;            // 0..11  (m-tile)
    const int bn = blockIdx.y;            // 0..31  (n-tile)
    const int bz = blockIdx.z;            // batch
    const int m0 = bm * 128, n0 = bn * 128;
    const int lane = t & 63, wv = t >> 6;
    const int quad = lane >> 4, l15 = lane & 15;
    const int wm = (wv & 1) * 64, wn = (wv >> 1) * 64;
    const float* xb = x + (size_t)bz * CIN * NSP;

    v4f acc[4][4];
    #pragma unroll
    for (int i = 0; i < 4; i++)
        #pragma unroll
        for (int j = 0; j < 4; j++) acc[i][j] = (v4f)0.f;

    const int cq = t >> 5, nq = t & 31;   // B-staging: thread owns 4c x 4n block

    for (int kk = 0; kk < CIN; kk += 32) {
        // stage A: w_qkv tile 128x32, fp32 -> bf16
        #pragma unroll
        for (int i = 0; i < 4; i++) {
            int v = t + 256 * i;
            int row = v >> 3, q = v & 7;
            const float4 f = *(const float4*)(wq + (size_t)(m0 + row) * CIN + kk + q * 4);
            union { unsigned short s[4]; uint2 u; } p;
            p.s[0] = f2bf(f.x); p.s[1] = f2bf(f.y); p.s[2] = f2bf(f.z); p.s[3] = f2bf(f.w);
            *(uint2*)(&As[row * 40 + q * 4]) = p.u;
        }
        // stage B: x tile 32c x 128n, transpose into [n][c] bf16
        {
            float4 rr[4];
            #pragma unroll
            for (int j = 0; j < 4; j++)
                rr[j] = *(const float4*)(xb + (size_t)(kk + cq * 4 + j) * NSP + n0 + nq * 4);
            #pragma unroll
            for (int i = 0; i < 4; i++) {
                union { unsigned short s[4]; uint2 u; } p;
                p.s[0] = f2bf(((const float*)&rr[0])[i]);
                p.s[1] = f2bf(((const float*)&rr[1])[i]);
                p.s[2] = f2bf(((const float*)&rr[2])[i]);
                p.s[3] = f2bf(((const float*)&rr[3])[i]);
                *(uint2*)(&Bs[(nq * 4 + i) * 40 + cq * 4]) = p.u;
            }
        }
        __syncthreads();
        v8s af[4], bfr[4];
        #pragma unroll
        for (int mi = 0; mi < 4; mi++) {
            const unsigned short* p = &As[(wm + mi * 16 + l15) * 40 + quad * 8];
            union { v8s v; uint2 u[2]; } r;
            r.u[0] = *(const uint2*)p; r.u[1] = *(const uint2*)(p + 4);
            af[mi] = r.v;
        }
        #pragma unroll
        for (int ni = 0; ni < 4; ni++) {
            const unsigned short* p = &Bs[(wn + ni * 16 + l15) * 40 + quad * 8];
            union { v8s v; uint2 u[2]; } r;
            r.u[0] = *(const uint2*)p; r.u[1] = *(const uint2*)(p + 4);
            bfr[ni] = r.v;
        }
        #pragma unroll
        for (int mi = 0; mi < 4; mi++)
            #pragma unroll
            for (int ni = 0; ni < 4; ni++)
                acc[mi][ni] = __builtin_amdgcn_mfma_f32_16x16x32_bf16(af[mi], bfr[ni], acc[mi][ni], 0, 0, 0);
        __syncthreads();
    }

    if (bm < 4) {
        // q part -> qT[b][n][o], 4 consecutive o per lane -> 8B stores
        #pragma unroll
        for (int mi = 0; mi < 4; mi++) {
            int o = m0 + wm + mi * 16 + quad * 4;
            #pragma unroll
            for (int ni = 0; ni < 4; ni++) {
                int n = n0 + wn + ni * 16 + l15;
                union { unsigned short s[4]; uint2 u; } p;
                p.s[0] = f2bf(acc[mi][ni][0]); p.s[1] = f2bf(acc[mi][ni][1]);
                p.s[2] = f2bf(acc[mi][ni][2]); p.s[3] = f2bf(acc[mi][ni][3]);
                *(uint2*)(qT + ((size_t)bz * NSP + n) * HID + o) = p.u;
            }
        }
    } else {
        #pragma unroll
        for (int mi = 0; mi < 4; mi++) {
            int rbase = m0 - 512 + wm + mi * 16 + quad * 4;
            #pragma unroll
            for (int ni = 0; ni < 4; ni++) {
                int n = n0 + wn + ni * 16 + l15;
                #pragma unroll
                for (int r = 0; r < 4; r++)
                    kv[((size_t)bz * 1024 + rbase + r) * NSP + n] = f2bf(acc[mi][ni][r]);
            }
        }
    }
}

// ---------------- K2: per-row softmax stats over n (rows = k rows) ----------------
__global__ __launch_bounds__(256) void k_stats(const unsigned short* __restrict__ kv,
                                               float* __restrict__ mArr,
                                               float* __restrict__ zArr) {
    const int t = threadIdx.x, lane = t & 63, wv = t >> 6;
    const int gw = blockIdx.x * 4 + wv;          // 0..8191 = b*512 + r
    const int b = gw >> 9, r = gw & 511;
    const unsigned short* row = kv + ((size_t)b * 1024 + r) * NSP;
    float vals[64];
    float m = -1e30f;
    #pragma unroll
    for (int i = 0; i < 8; i++) {
        union { uint4 u; unsigned short s[8]; } d;
        d.u = *(const uint4*)(row + i * 512 + lane * 8);
        #pragma unroll
        for (int j = 0; j < 8; j++) { float f = bf2f(d.s[j]); vals[i * 8 + j] = f; m = fmaxf(m, f); }
    }
    #pragma unroll
    for (int off = 32; off >= 1; off >>= 1) m = fmaxf(m, __shfl_xor(m, off));
    float s = 0.f;
    #pragma unroll
    for (int i = 0; i < 64; i++) s += __expf(vals[i] - m);
    #pragma unroll
    for (int off = 32; off >= 1; off >>= 1) s += __shfl_xor(s, off);
    if (lane == 0) { mArr[gw] = m; zArr[gw] = 1.0f / s; }
}

// ---------------- K3: context partials = softmax(k)(128x512chunk) @ v^T ----------------
__global__ __launch_bounds__(256) void k_ctx(const unsigned short* __restrict__ kv,
                                             const float* __restrict__ mArr,
                                             const float* __restrict__ zArr,
                                             float* __restrict__ ctxp) {
    __shared__ unsigned short As[128 * 40];   // softk [d][n'], stride 40
    __shared__ unsigned short Bs[128 * 40];   // v     [e][n'], stride 40
    const int t = threadIdx.x;
    const int ch = blockIdx.x;                 // 0..7
    const int bh = blockIdx.y;                 // 0..63
    const int b = bh >> 2, h = bh & 3;
    const int n0 = ch * 512;
    const int lane = t & 63, wv = t >> 6, quad = lane >> 4, l15 = lane & 15;
    const int wm = (wv & 1) * 64, wn = (wv >> 1) * 64;
    const unsigned short* kb = kv + ((size_t)b * 1024 + h * 128) * NSP;
    const unsigned short* vb = kv + ((size_t)b * 1024 + 512 + h * 128) * NSP;
    const float* mb = mArr + b * 512 + h * 128;
    const float* zb = zArr + b * 512 + h * 128;

    // rows this thread stages (independent of nn) -> hoist stats loads
    float mrow[4], zrow[4];
    #pragma unroll
    for (int i = 0; i < 4; i++) {
        int row = (t + 256 * i) >> 3;
        mrow[i] = mb[row]; zrow[i] = zb[row];
    }

    v4f acc[4][4];
    #pragma unroll
    for (int i = 0; i < 4; i++)
        #pragma unroll
        for (int j = 0; j < 4; j++) acc[i][j] = (v4f)0.f;

    for (int nn = n0; nn < n0 + 512; nn += 32) {
        #pragma unroll
        for (int i = 0; i < 4; i++) {
            int v = t + 256 * i;
            int row = v >> 3, q = v & 7;
            union { unsigned short s[4]; uint2 u; } d, p;
            d.u = *(const uint2*)(kb + (size_t)row * NSP + nn + q * 4);
            #pragma unroll
            for (int j = 0; j < 4; j++)
                p.s[j] = f2bf(__expf(bf2f(d.s[j]) - mrow[i]) * zrow[i]);
            *(uint2*)(&As[row * 40 + q * 4]) = p.u;
            d.u = *(const uint2*)(vb + (size_t)row * NSP + nn + q * 4);
            *(uint2*)(&Bs[row * 40 + q * 4]) = d.u;
        }
        __syncthreads();
        v8s af[4], bfr[4];
        #pragma unroll
        for (int mi = 0; mi < 4; mi++) {
            const unsigned short* p = &As[(wm + mi * 16 + l15) * 40 + quad * 8];
            union { v8s v; uint2 u[2]; } r;
            r.u[0] = *(const uint2*)p; r.u[1] = *(const uint2*)(p + 4);
            af[mi] = r.v;
        }
        #pragma unroll
        for (int ni = 0; ni < 4; ni++) {
            const unsigned short* p = &Bs[(wn + ni * 16 + l15) * 40 + quad * 8];
            union { v8s v; uint2 u[2]; } r;
            r.u[0] = *(const uint2*)p; r.u[1] = *(const uint2*)(p + 4);
            bfr[ni] = r.v;
        }
        #pragma unroll
        for (int mi = 0; mi < 4; mi++)
            #pragma unroll
            for (int ni = 0; ni < 4; ni++)
                acc[mi][ni] = __builtin_amdgcn_mfma_f32_16x16x32_bf16(af[mi], bfr[ni], acc[mi][ni], 0, 0, 0);
        __syncthreads();
    }
    float* outp = ctxp + ((size_t)bh * 8 + ch) * 16384;
    #pragma unroll
    for (int mi = 0; mi < 4; mi++)
        #pragma unroll
        for (int ni = 0; ni < 4; ni++)
            #pragma unroll
            for (int r = 0; r < 4; r++)
                outp[(wm + mi * 16 + quad * 4 + r) * 128 + wn + ni * 16 + l15] = acc[mi][ni][r];
}

// ---------------- K4: reduce ctx partials; Wc_h = w_out_h(256x128e) @ ctx^T(e x d) ----------------
__global__ __launch_bounds__(256) void k_redwc(const float* __restrict__ ctxp,
                                               const float* __restrict__ w_out,
                                               unsigned short* __restrict__ Wc) {
    __shared__ unsigned short Cs[128 * 136];   // ctx bf16 [d][e], stride 136
    const int t = threadIdx.x;
    const int bh = blockIdx.x;  const int b = bh >> 2, h = bh & 3;
    const int lane = t & 63, wv = t >> 6, quad = lane >> 4, l15 = lane & 15;

    #pragma unroll
    for (int i = 0; i < 16; i++) {
        int v = t + 256 * i;            // 4096 float4-quads
        int d = v >> 5, qq = v & 31;
        const float* p0 = ctxp + ((size_t)bh * 8) * 16384 + d * 128 + qq * 4;
        float4 s = *(const float4*)p0;
        #pragma unroll
        for (int c2 = 1; c2 < 8; c2++) {
            const float4 f = *(const float4*)(p0 + (size_t)c2 * 16384);
            s.x += f.x; s.y += f.y; s.z += f.z; s.w += f.w;
        }
        union { unsigned short us[4]; uint2 u; } p;
        p.us[0] = f2bf(s.x); p.us[1] = f2bf(s.y); p.us[2] = f2bf(s.z); p.us[3] = f2bf(s.w);
        *(uint2*)(&Cs[d * 136 + qq * 4]) = p.u;
    }
    __syncthreads();

    const int wm = wv * 64;   // wave covers 64 o-rows
    v4f acc[4][8];
    #pragma unroll
    for (int i = 0; i < 4; i++)
        #pragma unroll
        for (int j = 0; j < 8; j++) acc[i][j] = (v4f)0.f;

    for (int kk = 0; kk < 128; kk += 32) {
        v8s af[4], bfr[8];
        #pragma unroll
        for (int mi = 0; mi < 4; mi++) {
            int o = wm + mi * 16 + l15;
            const float* wp = w_out + (size_t)o * HID + h * 128 + kk + quad * 8;
            float4 f0 = *(const float4*)wp;
            float4 f1 = *(const float4*)(wp + 4);
            union { v8s v; unsigned short s[8]; } r;
            r.s[0] = f2bf(f0.x); r.s[1] = f2bf(f0.y); r.s[2] = f2bf(f0.z); r.s[3] = f2bf(f0.w);
            r.s[4] = f2bf(f1.x); r.s[5] = f2bf(f1.y); r.s[6] = f2bf(f1.z); r.s[7] = f2bf(f1.w);
            af[mi] = r.v;
        }
        #pragma unroll
        for (int ni = 0; ni < 8; ni++) {
            const unsigned short* p = &Cs[(ni * 16 + l15) * 136 + kk + quad * 8];
            union { v8s v; uint2 u[2]; } r;
            r.u[0] = *(const uint2*)p; r.u[1] = *(const uint2*)(p + 4);
            bfr[ni] = r.v;
        }
        #pragma unroll
        for (int mi = 0; mi < 4; mi++)
            #pragma unroll
            for (int ni = 0; ni < 8; ni++)
                acc[mi][ni] = __builtin_amdgcn_mfma_f32_16x16x32_bf16(af[mi], bfr[ni], acc[mi][ni], 0, 0, 0);
    }
    #pragma unroll
    for (int mi = 0; mi < 4; mi++)
        #pragma unroll
        for (int ni = 0; ni < 8; ni++)
            #pragma unroll
            for (int r = 0; r < 4; r++) {
                int o = wm + mi * 16 + quad * 4 + r;
                int d = ni * 16 + l15;
                Wc[((size_t)b * 256 + o) * HID + h * 128 + d] = f2bf(acc[mi][ni][r]);
            }
}

// ---------------- K5: y = Wc(256x512) @ q(512x4096) + b_out ----------------
__global__ __launch_bounds__(256) void k_out(const unsigned short* __restrict__ Wc,
                                             const unsigned short* __restrict__ qT,
                                             const float* __restrict__ b_out,
                                             float* __restrict__ y) {
    __shared__ unsigned short As[128 * 40];   // Wc [o][c], stride 40
    __shared__ unsigned short Bs[128 * 40];   // qT [n][c], stride 40
    const int t = threadIdx.x;
    const int bm = blockIdx.x;  // 0..1
    const int bn = blockIdx.y;  // 0..31
    const int bz = blockIdx.z;
    const int m0 = bm * 128, n0 = bn * 128;
    const int lane = t & 63, wv = t >> 6, quad = lane >> 4, l15 = lane & 15;
    const int wm = (wv & 1) * 64, wn = (wv >> 1) * 64;
    const unsigned short* Ab = Wc + (size_t)bz * 256 * HID;
    const unsigned short* Bb = qT + (size_t)bz * NSP * HID;

    v4f acc[4][4];
    #pragma unroll
    for (int i = 0; i < 4; i++)
        #pragma unroll
        for (int j = 0; j < 4; j++) acc[i][j] = (v4f)0.f;

    for (int kk = 0; kk < HID; kk += 32) {
        #pragma unroll
        for (int i = 0; i < 4; i++) {
            int v = t + 256 * i;
            int row = v >> 3, q = v & 7;
            *(uint2*)(&As[row * 40 + q * 4]) = *(const uint2*)(Ab + (size_t)(m0 + row) * HID + kk + q * 4);
            *(uint2*)(&Bs[row * 40 + q * 4]) = *(const uint2*)(Bb + (size_t)(n0 + row) * HID + kk + q * 4);
        }
        __syncthreads();
        v8s af[4], bfr[4];
        #pragma unroll
        for (int mi = 0; mi < 4; mi++) {
            const unsigned short* p = &As[(wm + mi * 16 + l15) * 40 + quad * 8];
            union { v8s v; uint2 u[2]; } r;
            r.u[0] = *(const uint2*)p; r.u[1] = *(const uint2*)(p + 4);
            af[mi] = r.v;
        }
        #pragma unroll
        for (int ni = 0; ni < 4; ni++) {
            const unsigned short* p = &Bs[(wn + ni * 16 + l15) * 40 + quad * 8];
            union { v8s v; uint2 u[2]; } r;
            r.u[0] = *(const uint2*)p; r.u[1] = *(const uint2*)(p + 4);
            bfr[ni] = r.v;
        }
        #pragma unroll
        for (int mi = 0; mi < 4; mi++)
            #pragma unroll
            for (int ni = 0; ni < 4; ni++)
                acc[mi][ni] = __builtin_amdgcn_mfma_f32_16x16x32_bf16(af[mi], bfr[ni], acc[mi][ni], 0, 0, 0);
        __syncthreads();
    }
    #pragma unroll
    for (int mi = 0; mi < 4; mi++) {
        int o = m0 + wm + mi * 16 + quad * 4;
        #pragma unroll
        for (int ni = 0; ni < 4; ni++) {
            int n = n0 + wn + ni * 16 + l15;
            #pragma unroll
            for (int r = 0; r < 4; r++)
                y[((size_t)bz * 256 + o + r) * NSP + n] = acc[mi][ni][r] + b_out[o + r];
        }
    }
}

extern "C" void kernel_launch(void* const* d_in, const int* in_sizes, int n_in,
                              void* d_out, int out_size, void* d_ws, size_t ws_size,
                              hipStream_t stream) {
    (void)in_sizes; (void)n_in; (void)out_size; (void)ws_size;
    const float* x     = (const float*)d_in[0];
    const float* w_qkv = (const float*)d_in[1];
    const float* w_out = (const float*)d_in[2];
    const float* b_out = (const float*)d_in[3];
    float* y = (float*)d_out;
    char* ws = (char*)d_ws;

    unsigned short* qT   = (unsigned short*)(ws);                 //  67,108,864 B
    unsigned short* kv   = (unsigned short*)(ws + 67108864);      // 134,217,728 B
    float*          mArr = (float*)(ws + 201326592);              //      32,768 B
    float*          zArr = (float*)(ws + 201359360);              //      32,768 B
    float*          ctxp = (float*)(ws + 201392128);              //  33,554,432 B
    unsigned short* Wc   = (unsigned short*)(ws + 234946560);     //   4,194,304 B

    k_qkv  <<<dim3(12, 32, 16), 256, 0, stream>>>(x, w_qkv, qT, kv);
    k_stats<<<dim3(2048),       256, 0, stream>>>(kv, mArr, zArr);
    k_ctx  <<<dim3(8, 64),      256, 0, stream>>>(kv, mArr, zArr, ctxp);
    k_redwc<<<dim3(64),         256, 0, stream>>>(ctxp, w_out, Wc);
    k_out  <<<dim3(2, 32, 16),  256, 0, stream>>>(Wc, qT, b_out, y);
}

// Round 2
// 332.196 us; speedup vs baseline: 1.2291x; 1.2291x over previous
//
#include <hip/hip_runtime.h>

#define BATCH 16
#define CIN   256
#define NSP   4096
#define HID   512

typedef short v8s __attribute__((ext_vector_type(8)));
typedef float v4f __attribute__((ext_vector_type(4)));

__device__ __forceinline__ unsigned short f2bf(float f) {
    union { float f; unsigned u; } a; a.f = f;
    unsigned r = a.u + 0x7fffu + ((a.u >> 16) & 1u);
    return (unsigned short)(r >> 16);
}
__device__ __forceinline__ float bf2f(unsigned short s) {
    union { unsigned u; float f; } a; a.u = ((unsigned)s) << 16;
    return a.f;
}

__device__ __forceinline__ void gld_lds16(const unsigned short* g, unsigned short* l) {
    __builtin_amdgcn_global_load_lds(
        (const __attribute__((address_space(1))) unsigned int*)g,
        (__attribute__((address_space(3))) unsigned int*)l,
        16, 0, 0);
}

// ---------------- P1: convert w_qkv fp32 -> bf16 [1536][256] ----------------
__global__ __launch_bounds__(256) void k_cvt_w(const float* __restrict__ wq,
                                               unsigned short* __restrict__ wbf) {
    const int t = blockIdx.x * 256 + threadIdx.x;   // 49152 threads x 8 elems
    const float4 f0 = *(const float4*)(wq + (size_t)t * 8);
    const float4 f1 = *(const float4*)(wq + (size_t)t * 8 + 4);
    union { unsigned short s[8]; uint4 u; } p;
    p.s[0] = f2bf(f0.x); p.s[1] = f2bf(f0.y); p.s[2] = f2bf(f0.z); p.s[3] = f2bf(f0.w);
    p.s[4] = f2bf(f1.x); p.s[5] = f2bf(f1.y); p.s[6] = f2bf(f1.z); p.s[7] = f2bf(f1.w);
    *(uint4*)(wbf + (size_t)t * 8) = p.u;
}

// ---------------- P2: transpose x [b][c][n] fp32 -> xT [b][n][c] bf16 ----------------
__global__ __launch_bounds__(256) void k_tr_x(const float* __restrict__ x,
                                              unsigned short* __restrict__ xT) {
    __shared__ float tile[64 * 65];
    const int t = threadIdx.x;
    const int n0 = blockIdx.x * 64, c0 = blockIdx.y * 64, bz = blockIdx.z;
    const float* xb = x + (size_t)bz * CIN * NSP;
    {
        const int nl = (t & 15) * 4, cl = t >> 4;          // cl 0..15
        #pragma unroll
        for (int i = 0; i < 4; i++) {
            int c = cl + i * 16;
            const float4 f = *(const float4*)(xb + (size_t)(c0 + c) * NSP + n0 + nl);
            *(float4*)(&tile[c * 65 + nl]) = f;
        }
    }
    __syncthreads();
    {
        const int cl4 = (t & 15) * 4, nl = t >> 4;         // nl 0..15
        #pragma unroll
        for (int i = 0; i < 4; i++) {
            int n = nl + i * 16;
            union { unsigned short s[4]; uint2 u; } p;
            #pragma unroll
            for (int j = 0; j < 4; j++)
                p.s[j] = f2bf(tile[(cl4 + j) * 65 + n]);
            *(uint2*)(xT + ((size_t)bz * NSP + n0 + n) * CIN + c0 + cl4) = p.u;
        }
    }
}

// ---------------- K1: qkv = wbf(1536x256) @ xT^T per batch (pure bf16 MFMA GEMM) ----
// q rows (o<512) written transposed qT[b][n][o] bf16; k,v rows written kv[b][o-512][n] bf16.
__global__ __launch_bounds__(256) void k_qkv(const unsigned short* __restrict__ wbf,
                                             const unsigned short* __restrict__ xT,
                                             unsigned short* __restrict__ qT,
                                             unsigned short* __restrict__ kv) {
    __shared__ __align__(16) unsigned short As[128 * 32];   // [m][k], unpadded (global_load_lds)
    __shared__ __align__(16) unsigned short Bs[128 * 32];   // [n][k], unpadded
    const int t = threadIdx.x;
    const int bm = blockIdx.x;            // 0..11
    const int bn = blockIdx.y;            // 0..31
    const int bz = blockIdx.z;
    const int m0 = bm * 128, n0 = bn * 128;
    const int lane = t & 63, wv = t >> 6;
    const int quad = lane >> 4, l15 = lane & 15;
    const int wm = (wv & 1) * 64, wn = (wv >> 1) * 64;

    // async staging: each wave fills 16 rows x 32 shorts per call (64 lanes x 16B)
    const int srow = lane >> 2, scol = (lane & 3) * 8;
    unsigned short* Al0 = As + wv * 16 * 32;     // wave-uniform LDS base
    unsigned short* Al1 = Al0 + 64 * 32;
    unsigned short* Bl0 = Bs + wv * 16 * 32;
    unsigned short* Bl1 = Bl0 + 64 * 32;
    const unsigned short* Ag0 = wbf + (size_t)(m0 + wv * 16 + srow) * CIN + scol;
    const unsigned short* Ag1 = Ag0 + 64 * CIN;
    const unsigned short* Bg0 = xT + ((size_t)bz * NSP + n0 + wv * 16 + srow) * CIN + scol;
    const unsigned short* Bg1 = Bg0 + 64 * CIN;

    v4f acc[4][4];
    #pragma unroll
    for (int i = 0; i < 4; i++)
        #pragma unroll
        for (int j = 0; j < 4; j++) acc[i][j] = (v4f)0.f;

    for (int kk = 0; kk < CIN; kk += 32) {
        gld_lds16(Ag0 + kk, Al0);
        gld_lds16(Ag1 + kk, Al1);
        gld_lds16(Bg0 + kk, Bl0);
        gld_lds16(Bg1 + kk, Bl1);
        __syncthreads();
        v8s af[4], bfr[4];
        #pragma unroll
        for (int mi = 0; mi < 4; mi++) {
            union { v8s v; uint4 u; } r;
            r.u = *(const uint4*)(&As[(wm + mi * 16 + l15) * 32 + quad * 8]);
            af[mi] = r.v;
        }
        #pragma unroll
        for (int ni = 0; ni < 4; ni++) {
            union { v8s v; uint4 u; } r;
            r.u = *(const uint4*)(&Bs[(wn + ni * 16 + l15) * 32 + quad * 8]);
            bfr[ni] = r.v;
        }
        #pragma unroll
        for (int mi = 0; mi < 4; mi++)
            #pragma unroll
            for (int ni = 0; ni < 4; ni++)
                acc[mi][ni] = __builtin_amdgcn_mfma_f32_16x16x32_bf16(af[mi], bfr[ni], acc[mi][ni], 0, 0, 0);
        __syncthreads();
    }

    if (bm < 4) {
        #pragma unroll
        for (int mi = 0; mi < 4; mi++) {
            int o = m0 + wm + mi * 16 + quad * 4;
            #pragma unroll
            for (int ni = 0; ni < 4; ni++) {
                int n = n0 + wn + ni * 16 + l15;
                union { unsigned short s[4]; uint2 u; } p;
                p.s[0] = f2bf(acc[mi][ni][0]); p.s[1] = f2bf(acc[mi][ni][1]);
                p.s[2] = f2bf(acc[mi][ni][2]); p.s[3] = f2bf(acc[mi][ni][3]);
                *(uint2*)(qT + ((size_t)bz * NSP + n) * HID + o) = p.u;
            }
        }
    } else {
        #pragma unroll
        for (int mi = 0; mi < 4; mi++) {
            int rbase = m0 - 512 + wm + mi * 16 + quad * 4;
            #pragma unroll
            for (int ni = 0; ni < 4; ni++) {
                int n = n0 + wn + ni * 16 + l15;
                #pragma unroll
                for (int r = 0; r < 4; r++)
                    kv[((size_t)bz * 1024 + rbase + r) * NSP + n] = f2bf(acc[mi][ni][r]);
            }
        }
    }
}

// ---------------- K2: per-row softmax stats over n (rows = k rows) ----------------
__global__ __launch_bounds__(256) void k_stats(const unsigned short* __restrict__ kv,
                                               float* __restrict__ mArr,
                                               float* __restrict__ zArr) {
    const int t = threadIdx.x, lane = t & 63, wv = t >> 6;
    const int gw = blockIdx.x * 4 + wv;          // 0..8191 = b*512 + r
    const int b = gw >> 9, r = gw & 511;
    const unsigned short* row = kv + ((size_t)b * 1024 + r) * NSP;
    float vals[64];
    float m = -1e30f;
    #pragma unroll
    for (int i = 0; i < 8; i++) {
        union { uint4 u; unsigned short s[8]; } d;
        d.u = *(const uint4*)(row + i * 512 + lane * 8);
        #pragma unroll
        for (int j = 0; j < 8; j++) { float f = bf2f(d.s[j]); vals[i * 8 + j] = f; m = fmaxf(m, f); }
    }
    #pragma unroll
    for (int off = 32; off >= 1; off >>= 1) m = fmaxf(m, __shfl_xor(m, off));
    float s = 0.f;
    #pragma unroll
    for (int i = 0; i < 64; i++) s += __expf(vals[i] - m);
    #pragma unroll
    for (int off = 32; off >= 1; off >>= 1) s += __shfl_xor(s, off);
    if (lane == 0) { mArr[gw] = m; zArr[gw] = 1.0f / s; }
}

// ---------------- K3: context partials = softmax(k)(128x512chunk) @ v^T ----------------
__global__ __launch_bounds__(256) void k_ctx(const unsigned short* __restrict__ kv,
                                             const float* __restrict__ mArr,
                                             const float* __restrict__ zArr,
                                             float* __restrict__ ctxp) {
    __shared__ unsigned short As[128 * 40];   // softk [d][n'], stride 40
    __shared__ unsigned short Bs[128 * 40];   // v     [e][n'], stride 40
    const int t = threadIdx.x;
    const int ch = blockIdx.x;                 // 0..7
    const int bh = blockIdx.y;                 // 0..63
    const int b = bh >> 2, h = bh & 3;
    const int n0 = ch * 512;
    const int lane = t & 63, wv = t >> 6, quad = lane >> 4, l15 = lane & 15;
    const int wm = (wv & 1) * 64, wn = (wv >> 1) * 64;
    const unsigned short* kb = kv + ((size_t)b * 1024 + h * 128) * NSP;
    const unsigned short* vb = kv + ((size_t)b * 1024 + 512 + h * 128) * NSP;
    const float* mb = mArr + b * 512 + h * 128;
    const float* zb = zArr + b * 512 + h * 128;

    float mrow[4], zrow[4];
    #pragma unroll
    for (int i = 0; i < 4; i++) {
        int row = (t + 256 * i) >> 3;
        mrow[i] = mb[row]; zrow[i] = zb[row];
    }

    v4f acc[4][4];
    #pragma unroll
    for (int i = 0; i < 4; i++)
        #pragma unroll
        for (int j = 0; j < 4; j++) acc[i][j] = (v4f)0.f;

    for (int nn = n0; nn < n0 + 512; nn += 32) {
        #pragma unroll
        for (int i = 0; i < 4; i++) {
            int v = t + 256 * i;
            int row = v >> 3, q = v & 7;
            union { unsigned short s[4]; uint2 u; } d, p;
            d.u = *(const uint2*)(kb + (size_t)row * NSP + nn + q * 4);
            #pragma unroll
            for (int j = 0; j < 4; j++)
                p.s[j] = f2bf(__expf(bf2f(d.s[j]) - mrow[i]) * zrow[i]);
            *(uint2*)(&As[row * 40 + q * 4]) = p.u;
            d.u = *(const uint2*)(vb + (size_t)row * NSP + nn + q * 4);
            *(uint2*)(&Bs[row * 40 + q * 4]) = d.u;
        }
        __syncthreads();
        v8s af[4], bfr[4];
        #pragma unroll
        for (int mi = 0; mi < 4; mi++) {
            const unsigned short* p = &As[(wm + mi * 16 + l15) * 40 + quad * 8];
            union { v8s v; uint2 u[2]; } r;
            r.u[0] = *(const uint2*)p; r.u[1] = *(const uint2*)(p + 4);
            af[mi] = r.v;
        }
        #pragma unroll
        for (int ni = 0; ni < 4; ni++) {
            const unsigned short* p = &Bs[(wn + ni * 16 + l15) * 40 + quad * 8];
            union { v8s v; uint2 u[2]; } r;
            r.u[0] = *(const uint2*)p; r.u[1] = *(const uint2*)(p + 4);
            bfr[ni] = r.v;
        }
        #pragma unroll
        for (int mi = 0; mi < 4; mi++)
            #pragma unroll
            for (int ni = 0; ni < 4; ni++)
                acc[mi][ni] = __builtin_amdgcn_mfma_f32_16x16x32_bf16(af[mi], bfr[ni], acc[mi][ni], 0, 0, 0);
        __syncthreads();
    }
    float* outp = ctxp + ((size_t)bh * 8 + ch) * 16384;
    #pragma unroll
    for (int mi = 0; mi < 4; mi++)
        #pragma unroll
        for (int ni = 0; ni < 4; ni++)
            #pragma unroll
            for (int r = 0; r < 4; r++)
                outp[(wm + mi * 16 + quad * 4 + r) * 128 + wn + ni * 16 + l15] = acc[mi][ni][r];
}

// ---------------- K4: reduce ctx partials; Wc_h = w_out_h(256x128e) @ ctx^T(e x d) ----------------
__global__ __launch_bounds__(256) void k_redwc(const float* __restrict__ ctxp,
                                               const float* __restrict__ w_out,
                                               unsigned short* __restrict__ Wc) {
    __shared__ unsigned short Cs[128 * 136];   // ctx bf16 [d][e], stride 136
    const int t = threadIdx.x;
    const int bh = blockIdx.x;  const int b = bh >> 2, h = bh & 3;
    const int lane = t & 63, wv = t >> 6, quad = lane >> 4, l15 = lane & 15;

    #pragma unroll
    for (int i = 0; i < 16; i++) {
        int v = t + 256 * i;            // 4096 float4-quads
        int d = v >> 5, qq = v & 31;
        const float* p0 = ctxp + ((size_t)bh * 8) * 16384 + d * 128 + qq * 4;
        float4 s = *(const float4*)p0;
        #pragma unroll
        for (int c2 = 1; c2 < 8; c2++) {
            const float4 f = *(const float4*)(p0 + (size_t)c2 * 16384);
            s.x += f.x; s.y += f.y; s.z += f.z; s.w += f.w;
        }
        union { unsigned short us[4]; uint2 u; } p;
        p.us[0] = f2bf(s.x); p.us[1] = f2bf(s.y); p.us[2] = f2bf(s.z); p.us[3] = f2bf(s.w);
        *(uint2*)(&Cs[d * 136 + qq * 4]) = p.u;
    }
    __syncthreads();

    const int wm = wv * 64;
    v4f acc[4][8];
    #pragma unroll
    for (int i = 0; i < 4; i++)
        #pragma unroll
        for (int j = 0; j < 8; j++) acc[i][j] = (v4f)0.f;

    for (int kk = 0; kk < 128; kk += 32) {
        v8s af[4], bfr[8];
        #pragma unroll
        for (int mi = 0; mi < 4; mi++) {
            int o = wm + mi * 16 + l15;
            const float* wp = w_out + (size_t)o * HID + h * 128 + kk + quad * 8;
            float4 f0 = *(const float4*)wp;
            float4 f1 = *(const float4*)(wp + 4);
            union { v8s v; unsigned short s[8]; } r;
            r.s[0] = f2bf(f0.x); r.s[1] = f2bf(f0.y); r.s[2] = f2bf(f0.z); r.s[3] = f2bf(f0.w);
            r.s[4] = f2bf(f1.x); r.s[5] = f2bf(f1.y); r.s[6] = f2bf(f1.z); r.s[7] = f2bf(f1.w);
            af[mi] = r.v;
        }
        #pragma unroll
        for (int ni = 0; ni < 8; ni++) {
            const unsigned short* p = &Cs[(ni * 16 + l15) * 136 + kk + quad * 8];
            union { v8s v; uint2 u[2]; } r;
            r.u[0] = *(const uint2*)p; r.u[1] = *(const uint2*)(p + 4);
            bfr[ni] = r.v;
        }
        #pragma unroll
        for (int mi = 0; mi < 4; mi++)
            #pragma unroll
            for (int ni = 0; ni < 8; ni++)
                acc[mi][ni] = __builtin_amdgcn_mfma_f32_16x16x32_bf16(af[mi], bfr[ni], acc[mi][ni], 0, 0, 0);
    }
    #pragma unroll
    for (int mi = 0; mi < 4; mi++)
        #pragma unroll
        for (int ni = 0; ni < 8; ni++)
            #pragma unroll
            for (int r = 0; r < 4; r++) {
                int o = wm + mi * 16 + quad * 4 + r;
                int d = ni * 16 + l15;
                Wc[((size_t)b * 256 + o) * HID + h * 128 + d] = f2bf(acc[mi][ni][r]);
            }
}

// ---------------- K5: y = Wc(256x512) @ q(512x4096) + b_out ----------------
__global__ __launch_bounds__(256) void k_out(const unsigned short* __restrict__ Wc,
                                             const unsigned short* __restrict__ qT,
                                             const float* __restrict__ b_out,
                                             float* __restrict__ y) {
    __shared__ unsigned short As[128 * 40];
    __shared__ unsigned short Bs[128 * 40];
    const int t = threadIdx.x;
    const int bm = blockIdx.x;  // 0..1
    const int bn = blockIdx.y;  // 0..31
    const int bz = blockIdx.z;
    const int m0 = bm * 128, n0 = bn * 128;
    const int lane = t & 63, wv = t >> 6, quad = lane >> 4, l15 = lane & 15;
    const int wm = (wv & 1) * 64, wn = (wv >> 1) * 64;
    const unsigned short* Ab = Wc + (size_t)bz * 256 * HID;
    const unsigned short* Bb = qT + (size_t)bz * NSP * HID;

    v4f acc[4][4];
    #pragma unroll
    for (int i = 0; i < 4; i++)
        #pragma unroll
        for (int j = 0; j < 4; j++) acc[i][j] = (v4f)0.f;

    for (int kk = 0; kk < HID; kk += 32) {
        #pragma unroll
        for (int i = 0; i < 4; i++) {
            int v = t + 256 * i;
            int row = v >> 3, q = v & 7;
            *(uint2*)(&As[row * 40 + q * 4]) = *(const uint2*)(Ab + (size_t)(m0 + row) * HID + kk + q * 4);
            *(uint2*)(&Bs[row * 40 + q * 4]) = *(const uint2*)(Bb + (size_t)(n0 + row) * HID + kk + q * 4);
        }
        __syncthreads();
        v8s af[4], bfr[4];
        #pragma unroll
        for (int mi = 0; mi < 4; mi++) {
            const unsigned short* p = &As[(wm + mi * 16 + l15) * 40 + quad * 8];
            union { v8s v; uint2 u[2]; } r;
            r.u[0] = *(const uint2*)p; r.u[1] = *(const uint2*)(p + 4);
            af[mi] = r.v;
        }
        #pragma unroll
        for (int ni = 0; ni < 4; ni++) {
            const unsigned short* p = &Bs[(wn + ni * 16 + l15) * 40 + quad * 8];
            union { v8s v; uint2 u[2]; } r;
            r.u[0] = *(const uint2*)p; r.u[1] = *(const uint2*)(p + 4);
            bfr[ni] = r.v;
        }
        #pragma unroll
        for (int mi = 0; mi < 4; mi++)
            #pragma unroll
            for (int ni = 0; ni < 4; ni++)
                acc[mi][ni] = __builtin_amdgcn_mfma_f32_16x16x32_bf16(af[mi], bfr[ni], acc[mi][ni], 0, 0, 0);
        __syncthreads();
    }
    #pragma unroll
    for (int mi = 0; mi < 4; mi++) {
        int o = m0 + wm + mi * 16 + quad * 4;
        #pragma unroll
        for (int ni = 0; ni < 4; ni++) {
            int n = n0 + wn + ni * 16 + l15;
            #pragma unroll
            for (int r = 0; r < 4; r++)
                y[((size_t)bz * 256 + o + r) * NSP + n] = acc[mi][ni][r] + b_out[o + r];
        }
    }
}

extern "C" void kernel_launch(void* const* d_in, const int* in_sizes, int n_in,
                              void* d_out, int out_size, void* d_ws, size_t ws_size,
                              hipStream_t stream) {
    (void)in_sizes; (void)n_in; (void)out_size; (void)ws_size;
    const float* x     = (const float*)d_in[0];
    const float* w_qkv = (const float*)d_in[1];
    const float* w_out = (const float*)d_in[2];
    const float* b_out = (const float*)d_in[3];
    float* y = (float*)d_out;
    char* ws = (char*)d_ws;

    unsigned short* qT   = (unsigned short*)(ws);                 //  67,108,864 B
    unsigned short* kv   = (unsigned short*)(ws + 67108864);      // 134,217,728 B
    float*          mArr = (float*)(ws + 201326592);              //      32,768 B
    float*          zArr = (float*)(ws + 201359360);              //      32,768 B
    // xT aliases ctxp (disjoint lifetimes: xT used only before k_ctx writes ctxp)
    unsigned short* xT   = (unsigned short*)(ws + 201392128);     //  33,554,432 B
    float*          ctxp = (float*)(ws + 201392128);              //  33,554,432 B
    // wbf aliases Wc (wbf used only before k_redwc writes Wc)
    unsigned short* wbf  = (unsigned short*)(ws + 234946560);     //     786,432 B
    unsigned short* Wc   = (unsigned short*)(ws + 234946560);     //   4,194,304 B

    k_cvt_w<<<dim3(192),        256, 0, stream>>>(w_qkv, wbf);
    k_tr_x <<<dim3(64, 4, 16),  256, 0, stream>>>(x, xT);
    k_qkv  <<<dim3(12, 32, 16), 256, 0, stream>>>(wbf, xT, qT, kv);
    k_stats<<<dim3(2048),       256, 0, stream>>>(kv, mArr, zArr);
    k_ctx  <<<dim3(8, 64),      256, 0, stream>>>(kv, mArr, zArr, ctxp);
    k_redwc<<<dim3(64),         256, 0, stream>>>(ctxp, w_out, Wc);
    k_out  <<<dim3(2, 32, 16),  256, 0, stream>>>(Wc, qT, b_out, y);
}

// Round 3
// 279.370 us; speedup vs baseline: 1.4615x; 1.1891x over previous
//
#include <hip/hip_runtime.h>

#define BATCH 16
#define CIN   256
#define NSP   4096
#define HID   512

typedef short v8s __attribute__((ext_vector_type(8)));
typedef float v4f __attribute__((ext_vector_type(4)));

__device__ __forceinline__ unsigned short f2bf(float f) {
    union { float f; unsigned u; } a; a.f = f;
    unsigned r = a.u + 0x7fffu + ((a.u >> 16) & 1u);
    return (unsigned short)(r >> 16);
}
__device__ __forceinline__ float bf2f(unsigned short s) {
    union { unsigned u; float f; } a; a.u = ((unsigned)s) << 16;
    return a.f;
}

__device__ __forceinline__ void gld_lds16(const unsigned short* g, unsigned short* l) {
    __builtin_amdgcn_global_load_lds(
        (const __attribute__((address_space(1))) unsigned int*)g,
        (__attribute__((address_space(3))) unsigned int*)l,
        16, 0, 0);
}

// ---------------- P1: convert w_qkv fp32 -> bf16 [1536][256] ----------------
__global__ __launch_bounds__(256) void k_cvt_w(const float* __restrict__ wq,
                                               unsigned short* __restrict__ wbf) {
    const int t = blockIdx.x * 256 + threadIdx.x;   // 49152 threads x 8 elems
    const float4 f0 = *(const float4*)(wq + (size_t)t * 8);
    const float4 f1 = *(const float4*)(wq + (size_t)t * 8 + 4);
    union { unsigned short s[8]; uint4 u; } p;
    p.s[0] = f2bf(f0.x); p.s[1] = f2bf(f0.y); p.s[2] = f2bf(f0.z); p.s[3] = f2bf(f0.w);
    p.s[4] = f2bf(f1.x); p.s[5] = f2bf(f1.y); p.s[6] = f2bf(f1.z); p.s[7] = f2bf(f1.w);
    *(uint4*)(wbf + (size_t)t * 8) = p.u;
}

// ---------------- P1b: wqT[c][u] = w_qkv[u][c] bf16, u<512 (q part, transposed) ----
__global__ __launch_bounds__(256) void k_tr_wq(const float* __restrict__ wq,
                                               unsigned short* __restrict__ wqT) {
    __shared__ float tile[64 * 65];
    const int t = threadIdx.x;
    const int u0 = blockIdx.x * 64, c0 = blockIdx.y * 64;
    {
        const int cl = (t & 15) * 4, ul = t >> 4;       // ul 0..15
        #pragma unroll
        for (int i = 0; i < 4; i++) {
            int u = ul + i * 16;
            const float4 f = *(const float4*)(wq + (size_t)(u0 + u) * CIN + c0 + cl);
            *(float4*)(&tile[u * 65 + cl]) = f;
        }
    }
    __syncthreads();
    {
        const int ul4 = (t & 15) * 4, cl = t >> 4;      // cl 0..15
        #pragma unroll
        for (int i = 0; i < 4; i++) {
            int c = cl + i * 16;
            union { unsigned short s[4]; uint2 u; } p;
            #pragma unroll
            for (int j = 0; j < 4; j++)
                p.s[j] = f2bf(tile[(ul4 + j) * 65 + c]);
            *(uint2*)(wqT + (size_t)(c0 + c) * HID + u0 + ul4) = p.u;
        }
    }
}

// ---------------- P2: transpose x [b][c][n] fp32 -> xT [b][n][c] bf16 ----------------
__global__ __launch_bounds__(256) void k_tr_x(const float* __restrict__ x,
                                              unsigned short* __restrict__ xT) {
    __shared__ float tile[64 * 65];
    const int t = threadIdx.x;
    const int n0 = blockIdx.x * 64, c0 = blockIdx.y * 64, bz = blockIdx.z;
    const float* xb = x + (size_t)bz * CIN * NSP;
    {
        const int nl = (t & 15) * 4, cl = t >> 4;
        #pragma unroll
        for (int i = 0; i < 4; i++) {
            int c = cl + i * 16;
            const float4 f = *(const float4*)(xb + (size_t)(c0 + c) * NSP + n0 + nl);
            *(float4*)(&tile[c * 65 + nl]) = f;
        }
    }
    __syncthreads();
    {
        const int cl4 = (t & 15) * 4, nl = t >> 4;
        #pragma unroll
        for (int i = 0; i < 4; i++) {
            int n = nl + i * 16;
            union { unsigned short s[4]; uint2 u; } p;
            #pragma unroll
            for (int j = 0; j < 4; j++)
                p.s[j] = f2bf(tile[(cl4 + j) * 65 + n]);
            *(uint2*)(xT + ((size_t)bz * NSP + n0 + n) * CIN + c0 + cl4) = p.u;
        }
    }
}

// ---------------- K1: kv = w_kv(1024x256) @ xT^T per batch; kv[b][row][n] bf16 ------
// XCD-swizzled 1D grid: each XCD owns 4 n-tiles per batch -> B stays L2-resident.
__global__ __launch_bounds__(256) void k_kv(const unsigned short* __restrict__ wbf,
                                            const unsigned short* __restrict__ xT,
                                            unsigned short* __restrict__ kv) {
    __shared__ __align__(16) unsigned short As[128 * 32];
    __shared__ __align__(16) unsigned short Bs[128 * 32];
    const int t = threadIdx.x;
    const int id = blockIdx.x;
    const int bz = id >> 8;
    const int r  = id & 255;
    const int xcd = r & 7, s = r >> 3;
    const int bn = (xcd << 2) | (s >> 3);   // 0..31
    const int bm = s & 7;                   // 0..7
    const int m0 = bm * 128, n0 = bn * 128;
    const int lane = t & 63, wv = t >> 6;
    const int quad = lane >> 4, l15 = lane & 15;
    const int wm = (wv & 1) * 64, wn = (wv >> 1) * 64;

    const int srow = lane >> 2, scol = (lane & 3) * 8;
    unsigned short* Al0 = As + wv * 16 * 32;
    unsigned short* Al1 = Al0 + 64 * 32;
    unsigned short* Bl0 = Bs + wv * 16 * 32;
    unsigned short* Bl1 = Bl0 + 64 * 32;
    const unsigned short* Ag0 = wbf + (size_t)(512 + m0 + wv * 16 + srow) * CIN + scol;
    const unsigned short* Ag1 = Ag0 + 64 * CIN;
    const unsigned short* Bg0 = xT + ((size_t)bz * NSP + n0 + wv * 16 + srow) * CIN + scol;
    const unsigned short* Bg1 = Bg0 + 64 * CIN;

    v4f acc[4][4];
    #pragma unroll
    for (int i = 0; i < 4; i++)
        #pragma unroll
        for (int j = 0; j < 4; j++) acc[i][j] = (v4f)0.f;

    for (int kk = 0; kk < CIN; kk += 32) {
        gld_lds16(Ag0 + kk, Al0);
        gld_lds16(Ag1 + kk, Al1);
        gld_lds16(Bg0 + kk, Bl0);
        gld_lds16(Bg1 + kk, Bl1);
        __syncthreads();
        v8s af[4], bfr[4];
        #pragma unroll
        for (int mi = 0; mi < 4; mi++) {
            union { v8s v; uint4 u; } rr;
            rr.u = *(const uint4*)(&As[(wm + mi * 16 + l15) * 32 + quad * 8]);
            af[mi] = rr.v;
        }
        #pragma unroll
        for (int ni = 0; ni < 4; ni++) {
            union { v8s v; uint4 u; } rr;
            rr.u = *(const uint4*)(&Bs[(wn + ni * 16 + l15) * 32 + quad * 8]);
            bfr[ni] = rr.v;
        }
        #pragma unroll
        for (int mi = 0; mi < 4; mi++)
            #pragma unroll
            for (int ni = 0; ni < 4; ni++)
                acc[mi][ni] = __builtin_amdgcn_mfma_f32_16x16x32_bf16(af[mi], bfr[ni], acc[mi][ni], 0, 0, 0);
        __syncthreads();
    }

    #pragma unroll
    for (int mi = 0; mi < 4; mi++) {
        int rbase = m0 + wm + mi * 16 + quad * 4;
        #pragma unroll
        for (int ni = 0; ni < 4; ni++) {
            int n = n0 + wn + ni * 16 + l15;
            #pragma unroll
            for (int rr = 0; rr < 4; rr++)
                kv[((size_t)bz * 1024 + rbase + rr) * NSP + n] = f2bf(acc[mi][ni][rr]);
        }
    }
}

// ---------------- K3: ctx partials = exp(k)(128 x 512chunk) @ v^T, + z partials -----
// No max subtraction (k ~ N(0,1), exp safe in fp32); z applied later in k_redwc.
__global__ __launch_bounds__(256) void k_ctx(const unsigned short* __restrict__ kv,
                                             float* __restrict__ ctxp,
                                             float* __restrict__ zp) {
    __shared__ unsigned short As[128 * 40];   // exp(k) [d][n'], stride 40
    __shared__ unsigned short Bs[128 * 40];   // v      [e][n'], stride 40
    const int t = threadIdx.x;
    const int ch = blockIdx.x;                 // 0..7
    const int bh = blockIdx.y;                 // 0..63
    const int b = bh >> 2, h = bh & 3;
    const int n0 = ch * 512;
    const int lane = t & 63, wv = t >> 6, quad = lane >> 4, l15 = lane & 15;
    const int wm = (wv & 1) * 64, wn = (wv >> 1) * 64;
    const unsigned short* kb = kv + ((size_t)b * 1024 + h * 128) * NSP;
    const unsigned short* vb = kv + ((size_t)b * 1024 + 512 + h * 128) * NSP;

    v4f acc[4][4];
    #pragma unroll
    for (int i = 0; i < 4; i++)
        #pragma unroll
        for (int j = 0; j < 4; j++) acc[i][j] = (v4f)0.f;

    float zacc[4] = {0.f, 0.f, 0.f, 0.f};

    for (int nn = n0; nn < n0 + 512; nn += 32) {
        #pragma unroll
        for (int i = 0; i < 4; i++) {
            int v = t + 256 * i;
            int row = v >> 3, q = v & 7;
            union { unsigned short s[4]; uint2 u; } d, p;
            d.u = *(const uint2*)(kb + (size_t)row * NSP + nn + q * 4);
            #pragma unroll
            for (int j = 0; j < 4; j++) {
                float e = __expf(bf2f(d.s[j]));
                zacc[i] += e;
                p.s[j] = f2bf(e);
            }
            *(uint2*)(&As[row * 40 + q * 4]) = p.u;
            d.u = *(const uint2*)(vb + (size_t)row * NSP + nn + q * 4);
            *(uint2*)(&Bs[row * 40 + q * 4]) = d.u;
        }
        __syncthreads();
        v8s af[4], bfr[4];
        #pragma unroll
        for (int mi = 0; mi < 4; mi++) {
            const unsigned short* p = &As[(wm + mi * 16 + l15) * 40 + quad * 8];
            union { v8s v; uint2 u[2]; } r;
            r.u[0] = *(const uint2*)p; r.u[1] = *(const uint2*)(p + 4);
            af[mi] = r.v;
        }
        #pragma unroll
        for (int ni = 0; ni < 4; ni++) {
            const unsigned short* p = &Bs[(wn + ni * 16 + l15) * 40 + quad * 8];
            union { v8s v; uint2 u[2]; } r;
            r.u[0] = *(const uint2*)p; r.u[1] = *(const uint2*)(p + 4);
            bfr[ni] = r.v;
        }
        #pragma unroll
        for (int mi = 0; mi < 4; mi++)
            #pragma unroll
            for (int ni = 0; ni < 4; ni++)
                acc[mi][ni] = __builtin_amdgcn_mfma_f32_16x16x32_bf16(af[mi], bfr[ni], acc[mi][ni], 0, 0, 0);
        __syncthreads();
    }

    // reduce z partials across the 8 threads staging each row
    #pragma unroll
    for (int i = 0; i < 4; i++) {
        float z = zacc[i];
        z += __shfl_xor(z, 1);
        z += __shfl_xor(z, 2);
        z += __shfl_xor(z, 4);
        if ((t & 7) == 0)
            zp[((size_t)bh * 8 + ch) * 128 + (t >> 3) + 32 * i] = z;
    }

    float* outp = ctxp + ((size_t)bh * 8 + ch) * 16384;
    #pragma unroll
    for (int mi = 0; mi < 4; mi++)
        #pragma unroll
        for (int ni = 0; ni < 4; ni++)
            #pragma unroll
            for (int r = 0; r < 4; r++)
                outp[(wm + mi * 16 + quad * 4 + r) * 128 + wn + ni * 16 + l15] = acc[mi][ni][r];
}

// ---------------- K4: reduce ctx+z partials; Wc_h = (w_out_h @ ctxu^T) * zinv[d] ----
__global__ __launch_bounds__(256) void k_redwc(const float* __restrict__ ctxp,
                                               const float* __restrict__ zp,
                                               const float* __restrict__ w_out,
                                               unsigned short* __restrict__ Wc) {
    __shared__ unsigned short Cs[128 * 136];   // ctxu bf16 [d][e], stride 136
    __shared__ float zinv[128];
    const int t = threadIdx.x;
    const int bh = blockIdx.x;  const int b = bh >> 2, h = bh & 3;
    const int lane = t & 63, wv = t >> 6, quad = lane >> 4, l15 = lane & 15;

    if (t < 128) {
        float z = 0.f;
        #pragma unroll
        for (int c2 = 0; c2 < 8; c2++)
            z += zp[((size_t)bh * 8 + c2) * 128 + t];
        zinv[t] = 1.0f / z;
    }
    #pragma unroll
    for (int i = 0; i < 16; i++) {
        int v = t + 256 * i;
        int d = v >> 5, qq = v & 31;
        const float* p0 = ctxp + ((size_t)bh * 8) * 16384 + d * 128 + qq * 4;
        float4 s = *(const float4*)p0;
        #pragma unroll
        for (int c2 = 1; c2 < 8; c2++) {
            const float4 f = *(const float4*)(p0 + (size_t)c2 * 16384);
            s.x += f.x; s.y += f.y; s.z += f.z; s.w += f.w;
        }
        union { unsigned short us[4]; uint2 u; } p;
        p.us[0] = f2bf(s.x); p.us[1] = f2bf(s.y); p.us[2] = f2bf(s.z); p.us[3] = f2bf(s.w);
        *(uint2*)(&Cs[d * 136 + qq * 4]) = p.u;
    }
    __syncthreads();

    const int wm = wv * 64;
    v4f acc[4][8];
    #pragma unroll
    for (int i = 0; i < 4; i++)
        #pragma unroll
        for (int j = 0; j < 8; j++) acc[i][j] = (v4f)0.f;

    for (int kk = 0; kk < 128; kk += 32) {
        v8s af[4], bfr[8];
        #pragma unroll
        for (int mi = 0; mi < 4; mi++) {
            int o = wm + mi * 16 + l15;
            const float* wp = w_out + (size_t)o * HID + h * 128 + kk + quad * 8;
            float4 f0 = *(const float4*)wp;
            float4 f1 = *(const float4*)(wp + 4);
            union { v8s v; unsigned short s[8]; } r;
            r.s[0] = f2bf(f0.x); r.s[1] = f2bf(f0.y); r.s[2] = f2bf(f0.z); r.s[3] = f2bf(f0.w);
            r.s[4] = f2bf(f1.x); r.s[5] = f2bf(f1.y); r.s[6] = f2bf(f1.z); r.s[7] = f2bf(f1.w);
            af[mi] = r.v;
        }
        #pragma unroll
        for (int ni = 0; ni < 8; ni++) {
            const unsigned short* p = &Cs[(ni * 16 + l15) * 136 + kk + quad * 8];
            union { v8s v; uint2 u[2]; } r;
            r.u[0] = *(const uint2*)p; r.u[1] = *(const uint2*)(p + 4);
            bfr[ni] = r.v;
        }
        #pragma unroll
        for (int mi = 0; mi < 4; mi++)
            #pragma unroll
            for (int ni = 0; ni < 8; ni++)
                acc[mi][ni] = __builtin_amdgcn_mfma_f32_16x16x32_bf16(af[mi], bfr[ni], acc[mi][ni], 0, 0, 0);
    }
    #pragma unroll
    for (int ni = 0; ni < 8; ni++) {
        int d = ni * 16 + l15;
        float zi = zinv[d];
        #pragma unroll
        for (int mi = 0; mi < 4; mi++)
            #pragma unroll
            for (int r = 0; r < 4; r++) {
                int o = wm + mi * 16 + quad * 4 + r;
                Wc[((size_t)b * 256 + o) * HID + h * 128 + d] = f2bf(acc[mi][ni][r] * zi);
            }
    }
}

// ---------------- K5: Weff[b] = Wc[b](256x512) @ wq_q^T  (via wqT[c][u]) ------------
__global__ __launch_bounds__(256) void k_chain(const unsigned short* __restrict__ Wc,
                                               const unsigned short* __restrict__ wqT,
                                               unsigned short* __restrict__ Weff) {
    __shared__ __align__(16) unsigned short As[128 * 32];
    __shared__ __align__(16) unsigned short Bs[128 * 32];
    const int t = threadIdx.x;
    const int m0 = blockIdx.x * 128, n0 = blockIdx.y * 128, bz = blockIdx.z;
    const int lane = t & 63, wv = t >> 6, quad = lane >> 4, l15 = lane & 15;
    const int wm = (wv & 1) * 64, wn = (wv >> 1) * 64;

    const int srow = lane >> 2, scol = (lane & 3) * 8;
    unsigned short* Al0 = As + wv * 16 * 32;
    unsigned short* Al1 = Al0 + 64 * 32;
    unsigned short* Bl0 = Bs + wv * 16 * 32;
    unsigned short* Bl1 = Bl0 + 64 * 32;
    const unsigned short* Ag0 = Wc + ((size_t)bz * 256 + m0 + wv * 16 + srow) * HID + scol;
    const unsigned short* Ag1 = Ag0 + 64 * HID;
    const unsigned short* Bg0 = wqT + (size_t)(n0 + wv * 16 + srow) * HID + scol;
    const unsigned short* Bg1 = Bg0 + 64 * HID;

    v4f acc[4][4];
    #pragma unroll
    for (int i = 0; i < 4; i++)
        #pragma unroll
        for (int j = 0; j < 4; j++) acc[i][j] = (v4f)0.f;

    for (int kk = 0; kk < HID; kk += 32) {
        gld_lds16(Ag0 + kk, Al0);
        gld_lds16(Ag1 + kk, Al1);
        gld_lds16(Bg0 + kk, Bl0);
        gld_lds16(Bg1 + kk, Bl1);
        __syncthreads();
        v8s af[4], bfr[4];
        #pragma unroll
        for (int mi = 0; mi < 4; mi++) {
            union { v8s v; uint4 u; } rr;
            rr.u = *(const uint4*)(&As[(wm + mi * 16 + l15) * 32 + quad * 8]);
            af[mi] = rr.v;
        }
        #pragma unroll
        for (int ni = 0; ni < 4; ni++) {
            union { v8s v; uint4 u; } rr;
            rr.u = *(const uint4*)(&Bs[(wn + ni * 16 + l15) * 32 + quad * 8]);
            bfr[ni] = rr.v;
        }
        #pragma unroll
        for (int mi = 0; mi < 4; mi++)
            #pragma unroll
            for (int ni = 0; ni < 4; ni++)
                acc[mi][ni] = __builtin_amdgcn_mfma_f32_16x16x32_bf16(af[mi], bfr[ni], acc[mi][ni], 0, 0, 0);
        __syncthreads();
    }
    #pragma unroll
    for (int mi = 0; mi < 4; mi++) {
        int obase = m0 + wm + mi * 16 + quad * 4;
        #pragma unroll
        for (int ni = 0; ni < 4; ni++) {
            int c = n0 + wn + ni * 16 + l15;
            #pragma unroll
            for (int r = 0; r < 4; r++)
                Weff[((size_t)bz * 256 + obase + r) * 256 + c] = f2bf(acc[mi][ni][r]);
        }
    }
}

// ---------------- K6: y = Weff(256x256) @ x(256x4096) + b_out -----------------------
__global__ __launch_bounds__(256) void k_y(const unsigned short* __restrict__ Weff,
                                           const unsigned short* __restrict__ xT,
                                           const float* __restrict__ b_out,
                                           float* __restrict__ y) {
    __shared__ __align__(16) unsigned short As[128 * 32];
    __shared__ __align__(16) unsigned short Bs[128 * 32];
    const int t = threadIdx.x;
    const int m0 = blockIdx.x * 128;   // 0..1
    const int n0 = blockIdx.y * 128;   // 0..31
    const int bz = blockIdx.z;
    const int lane = t & 63, wv = t >> 6, quad = lane >> 4, l15 = lane & 15;
    const int wm = (wv & 1) * 64, wn = (wv >> 1) * 64;

    const int srow = lane >> 2, scol = (lane & 3) * 8;
    unsigned short* Al0 = As + wv * 16 * 32;
    unsigned short* Al1 = Al0 + 64 * 32;
    unsigned short* Bl0 = Bs + wv * 16 * 32;
    unsigned short* Bl1 = Bl0 + 64 * 32;
    const unsigned short* Ag0 = Weff + ((size_t)bz * 256 + m0 + wv * 16 + srow) * CIN + scol;
    const unsigned short* Ag1 = Ag0 + 64 * CIN;
    const unsigned short* Bg0 = xT + ((size_t)bz * NSP + n0 + wv * 16 + srow) * CIN + scol;
    const unsigned short* Bg1 = Bg0 + 64 * CIN;

    v4f acc[4][4];
    #pragma unroll
    for (int i = 0; i < 4; i++)
        #pragma unroll
        for (int j = 0; j < 4; j++) acc[i][j] = (v4f)0.f;

    for (int kk = 0; kk < CIN; kk += 32) {
        gld_lds16(Ag0 + kk, Al0);
        gld_lds16(Ag1 + kk, Al1);
        gld_lds16(Bg0 + kk, Bl0);
        gld_lds16(Bg1 + kk, Bl1);
        __syncthreads();
        v8s af[4], bfr[4];
        #pragma unroll
        for (int mi = 0; mi < 4; mi++) {
            union { v8s v; uint4 u; } rr;
            rr.u = *(const uint4*)(&As[(wm + mi * 16 + l15) * 32 + quad * 8]);
            af[mi] = rr.v;
        }
        #pragma unroll
        for (int ni = 0; ni < 4; ni++) {
            union { v8s v; uint4 u; } rr;
            rr.u = *(const uint4*)(&Bs[(wn + ni * 16 + l15) * 32 + quad * 8]);
            bfr[ni] = rr.v;
        }
        #pragma unroll
        for (int mi = 0; mi < 4; mi++)
            #pragma unroll
            for (int ni = 0; ni < 4; ni++)
                acc[mi][ni] = __builtin_amdgcn_mfma_f32_16x16x32_bf16(af[mi], bfr[ni], acc[mi][ni], 0, 0, 0);
        __syncthreads();
    }
    #pragma unroll
    for (int mi = 0; mi < 4; mi++) {
        int o = m0 + wm + mi * 16 + quad * 4;
        #pragma unroll
        for (int ni = 0; ni < 4; ni++) {
            int n = n0 + wn + ni * 16 + l15;
            #pragma unroll
            for (int r = 0; r < 4; r++)
                y[((size_t)bz * 256 + o + r) * NSP + n] = acc[mi][ni][r] + b_out[o + r];
        }
    }
}

extern "C" void kernel_launch(void* const* d_in, const int* in_sizes, int n_in,
                              void* d_out, int out_size, void* d_ws, size_t ws_size,
                              hipStream_t stream) {
    (void)in_sizes; (void)n_in; (void)out_size; (void)ws_size;
    const float* x     = (const float*)d_in[0];
    const float* w_qkv = (const float*)d_in[1];
    const float* w_out = (const float*)d_in[2];
    const float* b_out = (const float*)d_in[3];
    float* y = (float*)d_out;
    char* ws = (char*)d_ws;

    unsigned short* xT   = (unsigned short*)(ws);                 //  33,554,432 B
    unsigned short* kv   = (unsigned short*)(ws + 33554432);      // 134,217,728 B
    float*          ctxp = (float*)(ws + 167772160);              //  33,554,432 B
    float*          zp   = (float*)(ws + 201326592);              //     262,144 B
    unsigned short* Wc   = (unsigned short*)(ws + 201588736);     //   4,194,304 B
    unsigned short* Weff = (unsigned short*)(ws + 205783040);     //   2,097,152 B
    unsigned short* wbf  = (unsigned short*)(ws + 207880192);     //     786,432 B
    unsigned short* wqT  = (unsigned short*)(ws + 208666624);     //     524,288 B

    k_cvt_w<<<dim3(192),        256, 0, stream>>>(w_qkv, wbf);
    k_tr_wq<<<dim3(8, 4),       256, 0, stream>>>(w_qkv, wqT);
    k_tr_x <<<dim3(64, 4, 16),  256, 0, stream>>>(x, xT);
    k_kv   <<<dim3(4096),       256, 0, stream>>>(wbf, xT, kv);
    k_ctx  <<<dim3(8, 64),      256, 0, stream>>>(kv, ctxp, zp);
    k_redwc<<<dim3(64),         256, 0, stream>>>(ctxp, zp, w_out, Wc);
    k_chain<<<dim3(2, 2, 16),   256, 0, stream>>>(Wc, wqT, Weff);
    k_y    <<<dim3(2, 32, 16),  256, 0, stream>>>(Weff, xT, b_out, y);
}

// Round 5
// 262.241 us; speedup vs baseline: 1.5569x; 1.0653x over previous
//
#include <hip/hip_runtime.h>

#define BATCH 16
#define CIN   256
#define NSP   4096
#define HID   512

typedef short v8s __attribute__((ext_vector_type(8)));
typedef float v4f __attribute__((ext_vector_type(4)));

__device__ __forceinline__ unsigned short f2bf(float f) {
    union { float f; unsigned u; } a; a.f = f;
    unsigned r = a.u + 0x7fffu + ((a.u >> 16) & 1u);
    return (unsigned short)(r >> 16);
}
__device__ __forceinline__ float bf2f(unsigned short s) {
    union { unsigned u; float f; } a; a.u = ((unsigned)s) << 16;
    return a.f;
}

__device__ __forceinline__ void gld_lds16(const unsigned short* g, unsigned short* l) {
    __builtin_amdgcn_global_load_lds(
        (const __attribute__((address_space(1))) unsigned int*)g,
        (__attribute__((address_space(3))) unsigned int*)l,
        16, 0, 0);
}

// ---------------- P1: convert w_qkv fp32 -> bf16 [1536][256] ----------------
__global__ __launch_bounds__(256) void k_cvt_w(const float* __restrict__ wq,
                                               unsigned short* __restrict__ wbf) {
    const int t = blockIdx.x * 256 + threadIdx.x;
    const float4 f0 = *(const float4*)(wq + (size_t)t * 8);
    const float4 f1 = *(const float4*)(wq + (size_t)t * 8 + 4);
    union { unsigned short s[8]; uint4 u; } p;
    p.s[0] = f2bf(f0.x); p.s[1] = f2bf(f0.y); p.s[2] = f2bf(f0.z); p.s[3] = f2bf(f0.w);
    p.s[4] = f2bf(f1.x); p.s[5] = f2bf(f1.y); p.s[6] = f2bf(f1.z); p.s[7] = f2bf(f1.w);
    *(uint4*)(wbf + (size_t)t * 8) = p.u;
}

// ---------------- P1b: wqT[c][u] = w_qkv[u][c] bf16, u<512 (q part, transposed) ----
__global__ __launch_bounds__(256) void k_tr_wq(const float* __restrict__ wq,
                                               unsigned short* __restrict__ wqT) {
    __shared__ float tile[64 * 65];
    const int t = threadIdx.x;
    const int u0 = blockIdx.x * 64, c0 = blockIdx.y * 64;
    {
        const int cl = (t & 15) * 4, ul = t >> 4;
        #pragma unroll
        for (int i = 0; i < 4; i++) {
            int u = ul + i * 16;
            const float4 f = *(const float4*)(wq + (size_t)(u0 + u) * CIN + c0 + cl);
            *(float4*)(&tile[u * 65 + cl]) = f;
        }
    }
    __syncthreads();
    {
        const int ul4 = (t & 15) * 4, cl = t >> 4;
        #pragma unroll
        for (int i = 0; i < 4; i++) {
            int c = cl + i * 16;
            union { unsigned short s[4]; uint2 u; } p;
            #pragma unroll
            for (int j = 0; j < 4; j++)
                p.s[j] = f2bf(tile[(ul4 + j) * 65 + c]);
            *(uint2*)(wqT + (size_t)(c0 + c) * HID + u0 + ul4) = p.u;
        }
    }
}

// ---------------- P2: x [b][c][n] fp32 -> xbf [b][c][n] bf16 AND xT [b][n][c] bf16 --
__global__ __launch_bounds__(256) void k_prep(const float* __restrict__ x,
                                              unsigned short* __restrict__ xbf,
                                              unsigned short* __restrict__ xT) {
    __shared__ float tile[64 * 65];
    const int t = threadIdx.x;
    const int n0 = blockIdx.x * 64, c0 = blockIdx.y * 64, bz = blockIdx.z;
    const float* xb = x + (size_t)bz * CIN * NSP;
    {
        const int nl = (t & 15) * 4, cl = t >> 4;
        #pragma unroll
        for (int i = 0; i < 4; i++) {
            int c = cl + i * 16;
            const float4 f = *(const float4*)(xb + (size_t)(c0 + c) * NSP + n0 + nl);
            *(float4*)(&tile[c * 65 + nl]) = f;
            union { unsigned short s[4]; uint2 u; } p;
            p.s[0] = f2bf(f.x); p.s[1] = f2bf(f.y); p.s[2] = f2bf(f.z); p.s[3] = f2bf(f.w);
            *(uint2*)(xbf + ((size_t)bz * CIN + c0 + c) * NSP + n0 + nl) = p.u;
        }
    }
    __syncthreads();
    {
        const int cl4 = (t & 15) * 4, nl = t >> 4;
        #pragma unroll
        for (int i = 0; i < 4; i++) {
            int n = nl + i * 16;
            union { unsigned short s[4]; uint2 u; } p;
            #pragma unroll
            for (int j = 0; j < 4; j++)
                p.s[j] = f2bf(tile[(cl4 + j) * 65 + n]);
            *(uint2*)(xT + ((size_t)bz * NSP + n0 + n) * CIN + c0 + cl4) = p.u;
        }
    }
}

// ---------------- K1: expk = exp(Wk @ x) per batch [b][512][n] + z partials --------
// z race fix: each wave-half (wv>>1) owns its own zp slot -> zp[row][bn*2 + half].
__global__ __launch_bounds__(256) void k_k(const unsigned short* __restrict__ wbf,
                                           const unsigned short* __restrict__ xT,
                                           unsigned short* __restrict__ expk,
                                           float* __restrict__ zp) {
    __shared__ __align__(16) unsigned short As[128 * 32];
    __shared__ __align__(16) unsigned short Bs[128 * 32];
    const int t = threadIdx.x;
    const int id = blockIdx.x;
    const int bz = id >> 7;
    const int r  = id & 127;
    const int xcd = r & 7, s = r >> 3;       // s 0..15
    const int bn = (xcd << 2) | (s & 3);     // 0..31
    const int bm = s >> 2;                   // 0..3
    const int m0 = bm * 128, n0 = bn * 128;
    const int lane = t & 63, wv = t >> 6;
    const int quad = lane >> 4, l15 = lane & 15;
    const int wm = (wv & 1) * 64, wn = (wv >> 1) * 64;

    const int srow = lane >> 2, scol = (lane & 3) * 8;
    unsigned short* Al0 = As + wv * 16 * 32;
    unsigned short* Al1 = Al0 + 64 * 32;
    unsigned short* Bl0 = Bs + wv * 16 * 32;
    unsigned short* Bl1 = Bl0 + 64 * 32;
    const unsigned short* Ag0 = wbf + (size_t)(512 + m0 + wv * 16 + srow) * CIN + scol;
    const unsigned short* Ag1 = Ag0 + 64 * CIN;
    const unsigned short* Bg0 = xT + ((size_t)bz * NSP + n0 + wv * 16 + srow) * CIN + scol;
    const unsigned short* Bg1 = Bg0 + 64 * CIN;

    v4f acc[4][4];
    #pragma unroll
    for (int i = 0; i < 4; i++)
        #pragma unroll
        for (int j = 0; j < 4; j++) acc[i][j] = (v4f)0.f;

    for (int kk = 0; kk < CIN; kk += 32) {
        gld_lds16(Ag0 + kk, Al0);
        gld_lds16(Ag1 + kk, Al1);
        gld_lds16(Bg0 + kk, Bl0);
        gld_lds16(Bg1 + kk, Bl1);
        __syncthreads();
        v8s af[4], bfr[4];
        #pragma unroll
        for (int mi = 0; mi < 4; mi++) {
            union { v8s v; uint4 u; } rr;
            rr.u = *(const uint4*)(&As[(wm + mi * 16 + l15) * 32 + quad * 8]);
            af[mi] = rr.v;
        }
        #pragma unroll
        for (int ni = 0; ni < 4; ni++) {
            union { v8s v; uint4 u; } rr;
            rr.u = *(const uint4*)(&Bs[(wn + ni * 16 + l15) * 32 + quad * 8]);
            bfr[ni] = rr.v;
        }
        #pragma unroll
        for (int mi = 0; mi < 4; mi++)
            #pragma unroll
            for (int ni = 0; ni < 4; ni++)
                acc[mi][ni] = __builtin_amdgcn_mfma_f32_16x16x32_bf16(af[mi], bfr[ni], acc[mi][ni], 0, 0, 0);
        __syncthreads();
    }

    // epilogue: exp, z-partials, bf16 store [d][n]
    float zr[4][4];
    #pragma unroll
    for (int mi = 0; mi < 4; mi++)
        #pragma unroll
        for (int rr = 0; rr < 4; rr++) zr[mi][rr] = 0.f;
    #pragma unroll
    for (int mi = 0; mi < 4; mi++)
        #pragma unroll
        for (int ni = 0; ni < 4; ni++)
            #pragma unroll
            for (int rr = 0; rr < 4; rr++) {
                float e = __expf(acc[mi][ni][rr]);
                acc[mi][ni][rr] = e;
                zr[mi][rr] += e;
            }
    #pragma unroll
    for (int mi = 0; mi < 4; mi++) {
        int row = m0 + wm + mi * 16 + quad * 4;
        #pragma unroll
        for (int ni = 0; ni < 4; ni++) {
            int n = n0 + wn + ni * 16 + l15;
            #pragma unroll
            for (int rr = 0; rr < 4; rr++)
                expk[((size_t)bz * 512 + row + rr) * NSP + n] = f2bf(acc[mi][ni][rr]);
        }
    }
    const int half = wv >> 1;   // which 64-column half of the tile this wave owns
    #pragma unroll
    for (int mi = 0; mi < 4; mi++)
        #pragma unroll
        for (int rr = 0; rr < 4; rr++) {
            float z = zr[mi][rr];
            z += __shfl_xor(z, 1); z += __shfl_xor(z, 2);
            z += __shfl_xor(z, 4); z += __shfl_xor(z, 8);
            if (l15 == 0)
                zp[((size_t)bz * 512 + m0 + wm + mi * 16 + quad * 4 + rr) * 64 + bn * 2 + half] = z;
        }
}

// ---------------- K2: S partials = expk(128d x 1024n) @ xbf(128c x 1024n)^T --------
__global__ __launch_bounds__(256) void k_S(const unsigned short* __restrict__ expk,
                                           const unsigned short* __restrict__ xbf,
                                           float* __restrict__ Sp) {
    __shared__ __align__(16) unsigned short As[128 * 32];
    __shared__ __align__(16) unsigned short Bs[128 * 32];
    const int t = threadIdx.x;
    const int id = blockIdx.x;              // 0..511
    const int hc = id >> 6;                 // 0..7
    const int h = hc >> 1, ch = hc & 1;
    const int bkc = id & 63;
    const int b = bkc >> 2, kc = bkc & 3;
    const int kw = kc * 1024;
    const int lane = t & 63, wv = t >> 6, quad = lane >> 4, l15 = lane & 15;
    const int wm = (wv & 1) * 64, wn = (wv >> 1) * 64;

    const int srow = lane >> 2, scol = (lane & 3) * 8;
    unsigned short* Al0 = As + wv * 16 * 32;
    unsigned short* Al1 = Al0 + 64 * 32;
    unsigned short* Bl0 = Bs + wv * 16 * 32;
    unsigned short* Bl1 = Bl0 + 64 * 32;
    const unsigned short* Ag0 = expk + ((size_t)b * 512 + h * 128 + wv * 16 + srow) * NSP + kw + scol;
    const unsigned short* Ag1 = Ag0 + 64 * NSP;
    const unsigned short* Bg0 = xbf + ((size_t)b * CIN + ch * 128 + wv * 16 + srow) * NSP + kw + scol;
    const unsigned short* Bg1 = Bg0 + 64 * NSP;

    v4f acc[4][4];
    #pragma unroll
    for (int i = 0; i < 4; i++)
        #pragma unroll
        for (int j = 0; j < 4; j++) acc[i][j] = (v4f)0.f;

    for (int kk = 0; kk < 1024; kk += 32) {
        gld_lds16(Ag0 + kk, Al0);
        gld_lds16(Ag1 + kk, Al1);
        gld_lds16(Bg0 + kk, Bl0);
        gld_lds16(Bg1 + kk, Bl1);
        __syncthreads();
        v8s af[4], bfr[4];
        #pragma unroll
        for (int mi = 0; mi < 4; mi++) {
            union { v8s v; uint4 u; } rr;
            rr.u = *(const uint4*)(&As[(wm + mi * 16 + l15) * 32 + quad * 8]);
            af[mi] = rr.v;
        }
        #pragma unroll
        for (int ni = 0; ni < 4; ni++) {
            union { v8s v; uint4 u; } rr;
            rr.u = *(const uint4*)(&Bs[(wn + ni * 16 + l15) * 32 + quad * 8]);
            bfr[ni] = rr.v;
        }
        #pragma unroll
        for (int mi = 0; mi < 4; mi++)
            #pragma unroll
            for (int ni = 0; ni < 4; ni++)
                acc[mi][ni] = __builtin_amdgcn_mfma_f32_16x16x32_bf16(af[mi], bfr[ni], acc[mi][ni], 0, 0, 0);
        __syncthreads();
    }

    // Sp layout: [(bh*2+ch)*4 + kc][128 d][128 c] fp32
    const int bh = b * 4 + h;
    float* outp = Sp + ((size_t)(bh * 2 + ch) * 4 + kc) * 16384;
    #pragma unroll
    for (int mi = 0; mi < 4; mi++)
        #pragma unroll
        for (int ni = 0; ni < 4; ni++)
            #pragma unroll
            for (int rr = 0; rr < 4; rr++)
                outp[(wm + mi * 16 + quad * 4 + rr) * 128 + wn + ni * 16 + l15] = acc[mi][ni][rr];
}

// ---------------- K3: reduce S partials -> Sred bf16 [bh][128 d][256 c] -------------
__global__ __launch_bounds__(256) void k_sred(const float* __restrict__ Sp,
                                              unsigned short* __restrict__ Sred) {
    const int qv = blockIdx.x * 256 + threadIdx.x;   // 524288 quads
    const int bh = qv >> 13, r = qv & 8191;
    const int dl = r >> 6, cq6 = r & 63;
    const int ch = cq6 >> 5, clq = cq6 & 31;
    const float* p = Sp + ((size_t)(bh * 2 + ch) * 4) * 16384 + dl * 128 + clq * 4;
    float4 s = *(const float4*)p;
    #pragma unroll
    for (int kc = 1; kc < 4; kc++) {
        const float4 f = *(const float4*)(p + (size_t)kc * 16384);
        s.x += f.x; s.y += f.y; s.z += f.z; s.w += f.w;
    }
    union { unsigned short us[4]; uint2 u; } pk;
    pk.us[0] = f2bf(s.x); pk.us[1] = f2bf(s.y); pk.us[2] = f2bf(s.z); pk.us[3] = f2bf(s.w);
    *(uint2*)(Sred + (size_t)bh * 32768 + dl * 256 + cq6 * 4) = pk.u;
}

// ---------------- K4: per bh: z-reduce; ctx = (Sred @ Wv^T)*zinv; Wc = w_out @ ctx^T -
__global__ __launch_bounds__(256) void k_redwc(const unsigned short* __restrict__ Sred,
                                               const float* __restrict__ zp,
                                               const unsigned short* __restrict__ wbf,
                                               const float* __restrict__ w_out,
                                               unsigned short* __restrict__ Wc) {
    __shared__ unsigned short Ds[128 * 136];   // ctx bf16 [d][e]
    __shared__ float zinv[128];
    const int t = threadIdx.x;
    const int bh = blockIdx.x;  const int b = bh >> 2, h = bh & 3;
    const int lane = t & 63, wv = t >> 6, quad = lane >> 4, l15 = lane & 15;

    if (t < 128) {
        float z = 0.f;
        #pragma unroll
        for (int nt = 0; nt < 64; nt++)
            z += zp[((size_t)b * 512 + h * 128 + t) * 64 + nt];
        zinv[t] = 1.0f / z;
    }
    __syncthreads();

    // GEMM-A: ctx[d][e] = sum_c Sred[d][c] * Wv_h[e][c]
    {
        const int wm = (wv & 1) * 64, wn = (wv >> 1) * 64;
        const unsigned short* Sb = Sred + (size_t)bh * 32768;
        const unsigned short* Vb = wbf + (size_t)(1024 + h * 128) * CIN;
        v4f acc[4][4];
        #pragma unroll
        for (int i = 0; i < 4; i++)
            #pragma unroll
            for (int j = 0; j < 4; j++) acc[i][j] = (v4f)0.f;
        for (int kk = 0; kk < CIN; kk += 32) {
            v8s af[4], bfr[4];
            #pragma unroll
            for (int mi = 0; mi < 4; mi++) {
                union { v8s v; uint4 u; } rr;
                rr.u = *(const uint4*)(Sb + (size_t)(wm + mi * 16 + l15) * 256 + kk + quad * 8);
                af[mi] = rr.v;
            }
            #pragma unroll
            for (int ni = 0; ni < 4; ni++) {
                union { v8s v; uint4 u; } rr;
                rr.u = *(const uint4*)(Vb + (size_t)(wn + ni * 16 + l15) * 256 + kk + quad * 8);
                bfr[ni] = rr.v;
            }
            #pragma unroll
            for (int mi = 0; mi < 4; mi++)
                #pragma unroll
                for (int ni = 0; ni < 4; ni++)
                    acc[mi][ni] = __builtin_amdgcn_mfma_f32_16x16x32_bf16(af[mi], bfr[ni], acc[mi][ni], 0, 0, 0);
        }
        float zq[4][4];
        #pragma unroll
        for (int mi = 0; mi < 4; mi++)
            #pragma unroll
            for (int rr = 0; rr < 4; rr++)
                zq[mi][rr] = zinv[wm + mi * 16 + quad * 4 + rr];
        #pragma unroll
        for (int mi = 0; mi < 4; mi++)
            #pragma unroll
            for (int ni = 0; ni < 4; ni++)
                #pragma unroll
                for (int rr = 0; rr < 4; rr++)
                    Ds[(wm + mi * 16 + quad * 4 + rr) * 136 + wn + ni * 16 + l15] =
                        f2bf(acc[mi][ni][rr] * zq[mi][rr]);
    }
    __syncthreads();

    // GEMM-B: Wc_h[o][d] = sum_e w_out[o][h*128+e] * ctx[d][e]
    {
        const int wm = wv * 64;
        v4f acc[4][8];
        #pragma unroll
        for (int i = 0; i < 4; i++)
            #pragma unroll
            for (int j = 0; j < 8; j++) acc[i][j] = (v4f)0.f;
        for (int kk = 0; kk < 128; kk += 32) {
            v8s af[4], bfr[8];
            #pragma unroll
            for (int mi = 0; mi < 4; mi++) {
                int o = wm + mi * 16 + l15;
                const float* wp = w_out + (size_t)o * HID + h * 128 + kk + quad * 8;
                float4 f0 = *(const float4*)wp;
                float4 f1 = *(const float4*)(wp + 4);
                union { v8s v; unsigned short s[8]; } r;
                r.s[0] = f2bf(f0.x); r.s[1] = f2bf(f0.y); r.s[2] = f2bf(f0.z); r.s[3] = f2bf(f0.w);
                r.s[4] = f2bf(f1.x); r.s[5] = f2bf(f1.y); r.s[6] = f2bf(f1.z); r.s[7] = f2bf(f1.w);
                af[mi] = r.v;
            }
            #pragma unroll
            for (int ni = 0; ni < 8; ni++) {
                const unsigned short* p = &Ds[(ni * 16 + l15) * 136 + kk + quad * 8];
                union { v8s v; uint4 u; } r;
                r.u = *(const uint4*)p;
                bfr[ni] = r.v;
            }
            #pragma unroll
            for (int mi = 0; mi < 4; mi++)
                #pragma unroll
                for (int ni = 0; ni < 8; ni++)
                    acc[mi][ni] = __builtin_amdgcn_mfma_f32_16x16x32_bf16(af[mi], bfr[ni], acc[mi][ni], 0, 0, 0);
        }
        #pragma unroll
        for (int ni = 0; ni < 8; ni++) {
            int d = ni * 16 + l15;
            #pragma unroll
            for (int mi = 0; mi < 4; mi++)
                #pragma unroll
                for (int rr = 0; rr < 4; rr++) {
                    int o = wm + mi * 16 + quad * 4 + rr;
                    Wc[((size_t)b * 256 + o) * HID + h * 128 + d] = f2bf(acc[mi][ni][rr]);
                }
        }
    }
}

// ---------------- K5: Weff[b] = Wc[b](256x512) @ wq_q^T  (via wqT[c][u]) ------------
__global__ __launch_bounds__(256) void k_chain(const unsigned short* __restrict__ Wc,
                                               const unsigned short* __restrict__ wqT,
                                               unsigned short* __restrict__ Weff) {
    __shared__ __align__(16) unsigned short As[128 * 32];
    __shared__ __align__(16) unsigned short Bs[128 * 32];
    const int t = threadIdx.x;
    const int m0 = blockIdx.x * 128, n0 = blockIdx.y * 128, bz = blockIdx.z;
    const int lane = t & 63, wv = t >> 6, quad = lane >> 4, l15 = lane & 15;
    const int wm = (wv & 1) * 64, wn = (wv >> 1) * 64;

    const int srow = lane >> 2, scol = (lane & 3) * 8;
    unsigned short* Al0 = As + wv * 16 * 32;
    unsigned short* Al1 = Al0 + 64 * 32;
    unsigned short* Bl0 = Bs + wv * 16 * 32;
    unsigned short* Bl1 = Bl0 + 64 * 32;
    const unsigned short* Ag0 = Wc + ((size_t)bz * 256 + m0 + wv * 16 + srow) * HID + scol;
    const unsigned short* Ag1 = Ag0 + 64 * HID;
    const unsigned short* Bg0 = wqT + (size_t)(n0 + wv * 16 + srow) * HID + scol;
    const unsigned short* Bg1 = Bg0 + 64 * HID;

    v4f acc[4][4];
    #pragma unroll
    for (int i = 0; i < 4; i++)
        #pragma unroll
        for (int j = 0; j < 4; j++) acc[i][j] = (v4f)0.f;

    for (int kk = 0; kk < HID; kk += 32) {
        gld_lds16(Ag0 + kk, Al0);
        gld_lds16(Ag1 + kk, Al1);
        gld_lds16(Bg0 + kk, Bl0);
        gld_lds16(Bg1 + kk, Bl1);
        __syncthreads();
        v8s af[4], bfr[4];
        #pragma unroll
        for (int mi = 0; mi < 4; mi++) {
            union { v8s v; uint4 u; } rr;
            rr.u = *(const uint4*)(&As[(wm + mi * 16 + l15) * 32 + quad * 8]);
            af[mi] = rr.v;
        }
        #pragma unroll
        for (int ni = 0; ni < 4; ni++) {
            union { v8s v; uint4 u; } rr;
            rr.u = *(const uint4*)(&Bs[(wn + ni * 16 + l15) * 32 + quad * 8]);
            bfr[ni] = rr.v;
        }
        #pragma unroll
        for (int mi = 0; mi < 4; mi++)
            #pragma unroll
            for (int ni = 0; ni < 4; ni++)
                acc[mi][ni] = __builtin_amdgcn_mfma_f32_16x16x32_bf16(af[mi], bfr[ni], acc[mi][ni], 0, 0, 0);
        __syncthreads();
    }
    #pragma unroll
    for (int mi = 0; mi < 4; mi++) {
        int obase = m0 + wm + mi * 16 + quad * 4;
        #pragma unroll
        for (int ni = 0; ni < 4; ni++) {
            int c = n0 + wn + ni * 16 + l15;
            #pragma unroll
            for (int r = 0; r < 4; r++)
                Weff[((size_t)bz * 256 + obase + r) * 256 + c] = f2bf(acc[mi][ni][r]);
        }
    }
}

// ---------------- K6: y = Weff(256x256) @ x(256x4096) + b_out -----------------------
__global__ __launch_bounds__(256) void k_y(const unsigned short* __restrict__ Weff,
                                           const unsigned short* __restrict__ xT,
                                           const float* __restrict__ b_out,
                                           float* __restrict__ y) {
    __shared__ __align__(16) unsigned short As[128 * 32];
    __shared__ __align__(16) unsigned short Bs[128 * 32];
    const int t = threadIdx.x;
    const int m0 = blockIdx.x * 128;
    const int n0 = blockIdx.y * 128;
    const int bz = blockIdx.z;
    const int lane = t & 63, wv = t >> 6, quad = lane >> 4, l15 = lane & 15;
    const int wm = (wv & 1) * 64, wn = (wv >> 1) * 64;

    const int srow = lane >> 2, scol = (lane & 3) * 8;
    unsigned short* Al0 = As + wv * 16 * 32;
    unsigned short* Al1 = Al0 + 64 * 32;
    unsigned short* Bl0 = Bs + wv * 16 * 32;
    unsigned short* Bl1 = Bl0 + 64 * 32;
    const unsigned short* Ag0 = Weff + ((size_t)bz * 256 + m0 + wv * 16 + srow) * CIN + scol;
    const unsigned short* Ag1 = Ag0 + 64 * CIN;
    const unsigned short* Bg0 = xT + ((size_t)bz * NSP + n0 + wv * 16 + srow) * CIN + scol;
    const unsigned short* Bg1 = Bg0 + 64 * CIN;

    v4f acc[4][4];
    #pragma unroll
    for (int i = 0; i < 4; i++)
        #pragma unroll
        for (int j = 0; j < 4; j++) acc[i][j] = (v4f)0.f;

    for (int kk = 0; kk < CIN; kk += 32) {
        gld_lds16(Ag0 + kk, Al0);
        gld_lds16(Ag1 + kk, Al1);
        gld_lds16(Bg0 + kk, Bl0);
        gld_lds16(Bg1 + kk, Bl1);
        __syncthreads();
        v8s af[4], bfr[4];
        #pragma unroll
        for (int mi = 0; mi < 4; mi++) {
            union { v8s v; uint4 u; } rr;
            rr.u = *(const uint4*)(&As[(wm + mi * 16 + l15) * 32 + quad * 8]);
            af[mi] = rr.v;
        }
        #pragma unroll
        for (int ni = 0; ni < 4; ni++) {
            union { v8s v; uint4 u; } rr;
            rr.u = *(const uint4*)(&Bs[(wn + ni * 16 + l15) * 32 + quad * 8]);
            bfr[ni] = rr.v;
        }
        #pragma unroll
        for (int mi = 0; mi < 4; mi++)
            #pragma unroll
            for (int ni = 0; ni < 4; ni++)
                acc[mi][ni] = __builtin_amdgcn_mfma_f32_16x16x32_bf16(af[mi], bfr[ni], acc[mi][ni], 0, 0, 0);
        __syncthreads();
    }
    #pragma unroll
    for (int mi = 0; mi < 4; mi++) {
        int o = m0 + wm + mi * 16 + quad * 4;
        #pragma unroll
        for (int ni = 0; ni < 4; ni++) {
            int n = n0 + wn + ni * 16 + l15;
            #pragma unroll
            for (int r = 0; r < 4; r++)
                y[((size_t)bz * 256 + o + r) * NSP + n] = acc[mi][ni][r] + b_out[o + r];
        }
    }
}

extern "C" void kernel_launch(void* const* d_in, const int* in_sizes, int n_in,
                              void* d_out, int out_size, void* d_ws, size_t ws_size,
                              hipStream_t stream) {
    (void)in_sizes; (void)n_in; (void)out_size; (void)ws_size;
    const float* x     = (const float*)d_in[0];
    const float* w_qkv = (const float*)d_in[1];
    const float* w_out = (const float*)d_in[2];
    const float* b_out = (const float*)d_in[3];
    float* y = (float*)d_out;
    char* ws = (char*)d_ws;

    unsigned short* xT   = (unsigned short*)(ws);                 //  33,554,432 B
    unsigned short* xbf  = (unsigned short*)(ws + 33554432);      //  33,554,432 B
    unsigned short* expk = (unsigned short*)(ws + 67108864);      //  67,108,864 B
    float*          Sp   = (float*)(ws + 134217728);              //  33,554,432 B
    float*          zp   = (float*)(ws + 167772160);              //   8,388,608 B  (512 rows x 64 slots x 16 b)
    unsigned short* Sred = (unsigned short*)(ws + 176160768);     //   4,194,304 B
    unsigned short* Wc   = (unsigned short*)(ws + 180355072);     //   4,194,304 B
    unsigned short* Weff = (unsigned short*)(ws + 184549376);     //   2,097,152 B
    unsigned short* wbf  = (unsigned short*)(ws + 186646528);     //     786,432 B
    unsigned short* wqT  = (unsigned short*)(ws + 187432960);     //     524,288 B

    k_cvt_w<<<dim3(192),        256, 0, stream>>>(w_qkv, wbf);
    k_tr_wq<<<dim3(8, 4),       256, 0, stream>>>(w_qkv, wqT);
    k_prep <<<dim3(64, 4, 16),  256, 0, stream>>>(x, xbf, xT);
    k_k    <<<dim3(2048),       256, 0, stream>>>(wbf, xT, expk, zp);
    k_S    <<<dim3(512),        256, 0, stream>>>(expk, xbf, Sp);
    k_sred <<<dim3(2048),       256, 0, stream>>>(Sp, Sred);
    k_redwc<<<dim3(64),         256, 0, stream>>>(Sred, zp, wbf, w_out, Wc);
    k_chain<<<dim3(2, 2, 16),   256, 0, stream>>>(Wc, wqT, Weff);
    k_y    <<<dim3(2, 32, 16),  256, 0, stream>>>(Weff, xT, b_out, y);
}

// Round 6
// 259.627 us; speedup vs baseline: 1.5726x; 1.0101x over previous
//
#include <hip/hip_runtime.h>

#define BATCH 16
#define CIN   256
#define NSP   4096
#define HID   512

typedef short v8s __attribute__((ext_vector_type(8)));
typedef float v4f __attribute__((ext_vector_type(4)));

__device__ __forceinline__ unsigned short f2bf(float f) {
    union { float f; unsigned u; } a; a.f = f;
    unsigned r = a.u + 0x7fffu + ((a.u >> 16) & 1u);
    return (unsigned short)(r >> 16);
}
__device__ __forceinline__ float bf2f(unsigned short s) {
    union { unsigned u; float f; } a; a.u = ((unsigned)s) << 16;
    return a.f;
}

__device__ __forceinline__ void gld_lds16(const unsigned short* g, unsigned short* l) {
    __builtin_amdgcn_global_load_lds(
        (const __attribute__((address_space(1))) unsigned int*)g,
        (__attribute__((address_space(3))) unsigned int*)l,
        16, 0, 0);
}

// ---------------- P1: merged weight prep: wbf (bf16 copy) + wqT (q-part transpose) --
__global__ __launch_bounds__(256) void k_w(const float* __restrict__ wq,
                                           unsigned short* __restrict__ wbf,
                                           unsigned short* __restrict__ wqT) {
    const int bid = blockIdx.x;
    if (bid < 192) {
        const int t = bid * 256 + threadIdx.x;
        const float4 f0 = *(const float4*)(wq + (size_t)t * 8);
        const float4 f1 = *(const float4*)(wq + (size_t)t * 8 + 4);
        union { unsigned short s[8]; uint4 u; } p;
        p.s[0] = f2bf(f0.x); p.s[1] = f2bf(f0.y); p.s[2] = f2bf(f0.z); p.s[3] = f2bf(f0.w);
        p.s[4] = f2bf(f1.x); p.s[5] = f2bf(f1.y); p.s[6] = f2bf(f1.z); p.s[7] = f2bf(f1.w);
        *(uint4*)(wbf + (size_t)t * 8) = p.u;
        return;
    }
    __shared__ float tile[64 * 65];
    const int bb = bid - 192;                 // 0..31
    const int u0 = (bb & 7) * 64, c0 = (bb >> 3) * 64;
    const int t = threadIdx.x;
    {
        const int cl = (t & 15) * 4, ul = t >> 4;
        #pragma unroll
        for (int i = 0; i < 4; i++) {
            int u = ul + i * 16;
            const float4 f = *(const float4*)(wq + (size_t)(u0 + u) * CIN + c0 + cl);
            *(float4*)(&tile[u * 65 + cl]) = f;
        }
    }
    __syncthreads();
    {
        const int ul4 = (t & 15) * 4, cl = t >> 4;
        #pragma unroll
        for (int i = 0; i < 4; i++) {
            int c = cl + i * 16;
            union { unsigned short s[4]; uint2 u; } p;
            #pragma unroll
            for (int j = 0; j < 4; j++)
                p.s[j] = f2bf(tile[(ul4 + j) * 65 + c]);
            *(uint2*)(wqT + (size_t)(c0 + c) * HID + u0 + ul4) = p.u;
        }
    }
}

// ---------------- P2: x [b][c][n] fp32 -> xbf [b][c][n] bf16 AND xT [b][n][c] bf16 --
__global__ __launch_bounds__(256) void k_prep(const float* __restrict__ x,
                                              unsigned short* __restrict__ xbf,
                                              unsigned short* __restrict__ xT) {
    __shared__ float tile[64 * 65];
    const int t = threadIdx.x;
    const int n0 = blockIdx.x * 64, c0 = blockIdx.y * 64, bz = blockIdx.z;
    const float* xb = x + (size_t)bz * CIN * NSP;
    {
        const int nl = (t & 15) * 4, cl = t >> 4;
        #pragma unroll
        for (int i = 0; i < 4; i++) {
            int c = cl + i * 16;
            const float4 f = *(const float4*)(xb + (size_t)(c0 + c) * NSP + n0 + nl);
            *(float4*)(&tile[c * 65 + nl]) = f;
            union { unsigned short s[4]; uint2 u; } p;
            p.s[0] = f2bf(f.x); p.s[1] = f2bf(f.y); p.s[2] = f2bf(f.z); p.s[3] = f2bf(f.w);
            *(uint2*)(xbf + ((size_t)bz * CIN + c0 + c) * NSP + n0 + nl) = p.u;
        }
    }
    __syncthreads();
    {
        const int cl4 = (t & 15) * 4, nl = t >> 4;
        #pragma unroll
        for (int i = 0; i < 4; i++) {
            int n = nl + i * 16;
            union { unsigned short s[4]; uint2 u; } p;
            #pragma unroll
            for (int j = 0; j < 4; j++)
                p.s[j] = f2bf(tile[(cl4 + j) * 65 + n]);
            *(uint2*)(xT + ((size_t)bz * NSP + n0 + n) * CIN + c0 + cl4) = p.u;
        }
    }
}

// ---------------- K1: expk = exp(Wk @ x), computed as C^T (M=n, N=d) ---------------
// Lane owns 4 consecutive n at fixed d -> uint2 coalesced stores; z-reduce via quads.
__global__ __launch_bounds__(256) void k_k(const unsigned short* __restrict__ wbf,
                                           const unsigned short* __restrict__ xT,
                                           unsigned short* __restrict__ expk,
                                           float* __restrict__ zp) {
    __shared__ __align__(16) unsigned short As[128 * 32];   // n-rows (xT)
    __shared__ __align__(16) unsigned short Bs[128 * 32];   // d-rows (wbf)
    const int t = threadIdx.x;
    const int id = blockIdx.x;
    const int bz = id >> 7;
    const int r  = id & 127;
    const int xcd = r & 7, s = r >> 3;
    const int bn = (xcd << 2) | (s & 3);     // n-tile 0..31
    const int bm = s >> 2;                   // d-tile 0..3
    const int d0 = bm * 128, n0 = bn * 128;
    const int lane = t & 63, wv = t >> 6;
    const int quad = lane >> 4, l15 = lane & 15;
    const int wmN = (wv & 1) * 64, wnD = (wv >> 1) * 64;

    const int srow = lane >> 2, scol = (lane & 3) * 8;
    unsigned short* Al0 = As + wv * 16 * 32;
    unsigned short* Al1 = Al0 + 64 * 32;
    unsigned short* Bl0 = Bs + wv * 16 * 32;
    unsigned short* Bl1 = Bl0 + 64 * 32;
    const unsigned short* Ag0 = xT + ((size_t)bz * NSP + n0 + wv * 16 + srow) * CIN + scol;
    const unsigned short* Ag1 = Ag0 + 64 * CIN;
    const unsigned short* Bg0 = wbf + (size_t)(512 + d0 + wv * 16 + srow) * CIN + scol;
    const unsigned short* Bg1 = Bg0 + 64 * CIN;

    v4f acc[4][4];
    #pragma unroll
    for (int i = 0; i < 4; i++)
        #pragma unroll
        for (int j = 0; j < 4; j++) acc[i][j] = (v4f)0.f;

    for (int kk = 0; kk < CIN; kk += 32) {
        gld_lds16(Ag0 + kk, Al0);
        gld_lds16(Ag1 + kk, Al1);
        gld_lds16(Bg0 + kk, Bl0);
        gld_lds16(Bg1 + kk, Bl1);
        __syncthreads();
        v8s af[4], bfr[4];
        #pragma unroll
        for (int mi = 0; mi < 4; mi++) {
            union { v8s v; uint4 u; } rr;
            rr.u = *(const uint4*)(&As[(wmN + mi * 16 + l15) * 32 + quad * 8]);
            af[mi] = rr.v;
        }
        #pragma unroll
        for (int ni = 0; ni < 4; ni++) {
            union { v8s v; uint4 u; } rr;
            rr.u = *(const uint4*)(&Bs[(wnD + ni * 16 + l15) * 32 + quad * 8]);
            bfr[ni] = rr.v;
        }
        #pragma unroll
        for (int mi = 0; mi < 4; mi++)
            #pragma unroll
            for (int ni = 0; ni < 4; ni++)
                acc[mi][ni] = __builtin_amdgcn_mfma_f32_16x16x32_bf16(af[mi], bfr[ni], acc[mi][ni], 0, 0, 0);
        __syncthreads();
    }

    // epilogue: exp + coalesced uint2 stores; lane d fixed per ni
    float zacc[4] = {0.f, 0.f, 0.f, 0.f};
    #pragma unroll
    for (int ni = 0; ni < 4; ni++) {
        const int d = d0 + wnD + ni * 16 + l15;
        #pragma unroll
        for (int mi = 0; mi < 4; mi++) {
            const int nb = n0 + wmN + mi * 16 + quad * 4;
            union { unsigned short s[4]; uint2 u; } p;
            #pragma unroll
            for (int rr = 0; rr < 4; rr++) {
                float e = __expf(acc[mi][ni][rr]);
                zacc[ni] += e;
                p.s[rr] = f2bf(e);
            }
            *(uint2*)(expk + ((size_t)bz * 512 + d) * NSP + nb) = p.u;
        }
    }
    #pragma unroll
    for (int ni = 0; ni < 4; ni++) {
        float z = zacc[ni];
        z += __shfl_xor(z, 16);
        z += __shfl_xor(z, 32);
        if (quad == 0)
            zp[((size_t)bz * 512 + d0 + wnD + ni * 16 + l15) * 64 + bn * 2 + (wv & 1)] = z;
    }
}

// ---------------- K2: S partials, computed as C^T (M=c, N=d) -> float4 stores -------
// S[d][c] = sum_n expk[d][n] * x[c][n].  Split-K over n (4 chunks of 1024).
__global__ __launch_bounds__(256) void k_S(const unsigned short* __restrict__ expk,
                                           const unsigned short* __restrict__ xbf,
                                           float* __restrict__ Sp) {
    __shared__ __align__(16) unsigned short As[128 * 32];   // c-rows (xbf)
    __shared__ __align__(16) unsigned short Bs[128 * 32];   // d-rows (expk)
    const int t = threadIdx.x;
    const int id = blockIdx.x;              // 0..511
    const int hc = id >> 6;                 // 0..7
    const int h = hc >> 1, ch = hc & 1;
    const int bkc = id & 63;
    const int b = bkc >> 2, kc = bkc & 3;
    const int kw = kc * 1024;
    const int lane = t & 63, wv = t >> 6, quad = lane >> 4, l15 = lane & 15;
    const int wmC = (wv & 1) * 64, wnD = (wv >> 1) * 64;

    const int srow = lane >> 2, scol = (lane & 3) * 8;
    unsigned short* Al0 = As + wv * 16 * 32;
    unsigned short* Al1 = Al0 + 64 * 32;
    unsigned short* Bl0 = Bs + wv * 16 * 32;
    unsigned short* Bl1 = Bl0 + 64 * 32;
    const unsigned short* Ag0 = xbf + ((size_t)b * CIN + ch * 128 + wv * 16 + srow) * NSP + kw + scol;
    const unsigned short* Ag1 = Ag0 + 64 * NSP;
    const unsigned short* Bg0 = expk + ((size_t)b * 512 + h * 128 + wv * 16 + srow) * NSP + kw + scol;
    const unsigned short* Bg1 = Bg0 + 64 * NSP;

    v4f acc[4][4];
    #pragma unroll
    for (int i = 0; i < 4; i++)
        #pragma unroll
        for (int j = 0; j < 4; j++) acc[i][j] = (v4f)0.f;

    for (int kk = 0; kk < 1024; kk += 32) {
        gld_lds16(Ag0 + kk, Al0);
        gld_lds16(Ag1 + kk, Al1);
        gld_lds16(Bg0 + kk, Bl0);
        gld_lds16(Bg1 + kk, Bl1);
        __syncthreads();
        v8s af[4], bfr[4];
        #pragma unroll
        for (int mi = 0; mi < 4; mi++) {
            union { v8s v; uint4 u; } rr;
            rr.u = *(const uint4*)(&As[(wmC + mi * 16 + l15) * 32 + quad * 8]);
            af[mi] = rr.v;
        }
        #pragma unroll
        for (int ni = 0; ni < 4; ni++) {
            union { v8s v; uint4 u; } rr;
            rr.u = *(const uint4*)(&Bs[(wnD + ni * 16 + l15) * 32 + quad * 8]);
            bfr[ni] = rr.v;
        }
        #pragma unroll
        for (int mi = 0; mi < 4; mi++)
            #pragma unroll
            for (int ni = 0; ni < 4; ni++)
                acc[mi][ni] = __builtin_amdgcn_mfma_f32_16x16x32_bf16(af[mi], bfr[ni], acc[mi][ni], 0, 0, 0);
        __syncthreads();
    }

    // Sp layout: [(bh*2+ch)*4 + kc][128 d][128 c] fp32; lane's 4 vals = consecutive c
    const int bh = b * 4 + h;
    float* outp = Sp + ((size_t)(bh * 2 + ch) * 4 + kc) * 16384;
    #pragma unroll
    for (int ni = 0; ni < 4; ni++) {
        const int d = wnD + ni * 16 + l15;
        #pragma unroll
        for (int mi = 0; mi < 4; mi++) {
            const int c = wmC + mi * 16 + quad * 4;
            *(v4f*)(outp + d * 128 + c) = acc[mi][ni];
        }
    }
}

// ---------------- K3: reduce S partials -> Sred bf16 [bh][128 d][256 c] -------------
__global__ __launch_bounds__(256) void k_sred(const float* __restrict__ Sp,
                                              unsigned short* __restrict__ Sred) {
    const int qv = blockIdx.x * 256 + threadIdx.x;   // 524288 quads
    const int bh = qv >> 13, r = qv & 8191;
    const int dl = r >> 6, cq6 = r & 63;
    const int ch = cq6 >> 5, clq = cq6 & 31;
    const float* p = Sp + ((size_t)(bh * 2 + ch) * 4) * 16384 + dl * 128 + clq * 4;
    float4 s = *(const float4*)p;
    #pragma unroll
    for (int kc = 1; kc < 4; kc++) {
        const float4 f = *(const float4*)(p + (size_t)kc * 16384);
        s.x += f.x; s.y += f.y; s.z += f.z; s.w += f.w;
    }
    union { unsigned short us[4]; uint2 u; } pk;
    pk.us[0] = f2bf(s.x); pk.us[1] = f2bf(s.y); pk.us[2] = f2bf(s.z); pk.us[3] = f2bf(s.w);
    *(uint2*)(Sred + (size_t)bh * 32768 + dl * 256 + cq6 * 4) = pk.u;
}

// ---------------- K4: per bh: z-reduce; ctx = (Sred @ Wv^T)*zinv; Wc = w_out @ ctx^T -
__global__ __launch_bounds__(256) void k_redwc(const unsigned short* __restrict__ Sred,
                                               const float* __restrict__ zp,
                                               const unsigned short* __restrict__ wbf,
                                               const float* __restrict__ w_out,
                                               unsigned short* __restrict__ Wc) {
    __shared__ unsigned short Ds[128 * 136];   // ctx bf16 [d][e]
    __shared__ float zinv[128];
    const int t = threadIdx.x;
    const int bh = blockIdx.x;  const int b = bh >> 2, h = bh & 3;
    const int lane = t & 63, wv = t >> 6, quad = lane >> 4, l15 = lane & 15;

    if (t < 128) {
        float z = 0.f;
        #pragma unroll
        for (int nt = 0; nt < 64; nt++)
            z += zp[((size_t)b * 512 + h * 128 + t) * 64 + nt];
        zinv[t] = 1.0f / z;
    }
    __syncthreads();

    // GEMM-A: ctx[d][e] = sum_c Sred[d][c] * Wv_h[e][c]
    {
        const int wm = (wv & 1) * 64, wn = (wv >> 1) * 64;
        const unsigned short* Sb = Sred + (size_t)bh * 32768;
        const unsigned short* Vb = wbf + (size_t)(1024 + h * 128) * CIN;
        v4f acc[4][4];
        #pragma unroll
        for (int i = 0; i < 4; i++)
            #pragma unroll
            for (int j = 0; j < 4; j++) acc[i][j] = (v4f)0.f;
        for (int kk = 0; kk < CIN; kk += 32) {
            v8s af[4], bfr[4];
            #pragma unroll
            for (int mi = 0; mi < 4; mi++) {
                union { v8s v; uint4 u; } rr;
                rr.u = *(const uint4*)(Sb + (size_t)(wm + mi * 16 + l15) * 256 + kk + quad * 8);
                af[mi] = rr.v;
            }
            #pragma unroll
            for (int ni = 0; ni < 4; ni++) {
                union { v8s v; uint4 u; } rr;
                rr.u = *(const uint4*)(Vb + (size_t)(wn + ni * 16 + l15) * 256 + kk + quad * 8);
                bfr[ni] = rr.v;
            }
            #pragma unroll
            for (int mi = 0; mi < 4; mi++)
                #pragma unroll
                for (int ni = 0; ni < 4; ni++)
                    acc[mi][ni] = __builtin_amdgcn_mfma_f32_16x16x32_bf16(af[mi], bfr[ni], acc[mi][ni], 0, 0, 0);
        }
        float zq[4][4];
        #pragma unroll
        for (int mi = 0; mi < 4; mi++)
            #pragma unroll
            for (int rr = 0; rr < 4; rr++)
                zq[mi][rr] = zinv[wm + mi * 16 + quad * 4 + rr];
        #pragma unroll
        for (int mi = 0; mi < 4; mi++)
            #pragma unroll
            for (int ni = 0; ni < 4; ni++)
                #pragma unroll
                for (int rr = 0; rr < 4; rr++)
                    Ds[(wm + mi * 16 + quad * 4 + rr) * 136 + wn + ni * 16 + l15] =
                        f2bf(acc[mi][ni][rr] * zq[mi][rr]);
    }
    __syncthreads();

    // GEMM-B: Wc_h[o][d] = sum_e w_out[o][h*128+e] * ctx[d][e]
    {
        const int wm = wv * 64;
        v4f acc[4][8];
        #pragma unroll
        for (int i = 0; i < 4; i++)
            #pragma unroll
            for (int j = 0; j < 8; j++) acc[i][j] = (v4f)0.f;
        for (int kk = 0; kk < 128; kk += 32) {
            v8s af[4], bfr[8];
            #pragma unroll
            for (int mi = 0; mi < 4; mi++) {
                int o = wm + mi * 16 + l15;
                const float* wp = w_out + (size_t)o * HID + h * 128 + kk + quad * 8;
                float4 f0 = *(const float4*)wp;
                float4 f1 = *(const float4*)(wp + 4);
                union { v8s v; unsigned short s[8]; } r;
                r.s[0] = f2bf(f0.x); r.s[1] = f2bf(f0.y); r.s[2] = f2bf(f0.z); r.s[3] = f2bf(f0.w);
                r.s[4] = f2bf(f1.x); r.s[5] = f2bf(f1.y); r.s[6] = f2bf(f1.z); r.s[7] = f2bf(f1.w);
                af[mi] = r.v;
            }
            #pragma unroll
            for (int ni = 0; ni < 8; ni++) {
                const unsigned short* p = &Ds[(ni * 16 + l15) * 136 + kk + quad * 8];
                union { v8s v; uint4 u; } r;
                r.u = *(const uint4*)p;
                bfr[ni] = r.v;
            }
            #pragma unroll
            for (int mi = 0; mi < 4; mi++)
                #pragma unroll
                for (int ni = 0; ni < 8; ni++)
                    acc[mi][ni] = __builtin_amdgcn_mfma_f32_16x16x32_bf16(af[mi], bfr[ni], acc[mi][ni], 0, 0, 0);
        }
        #pragma unroll
        for (int ni = 0; ni < 8; ni++) {
            int d = ni * 16 + l15;
            #pragma unroll
            for (int mi = 0; mi < 4; mi++)
                #pragma unroll
                for (int rr = 0; rr < 4; rr++) {
                    int o = wm + mi * 16 + quad * 4 + rr;
                    Wc[((size_t)b * 256 + o) * HID + h * 128 + d] = f2bf(acc[mi][ni][rr]);
                }
        }
    }
}

// ---------------- K5: Weff = Wc @ wq_q^T, computed as C^T (M=c, N=o) ----------------
__global__ __launch_bounds__(256) void k_chain(const unsigned short* __restrict__ Wc,
                                               const unsigned short* __restrict__ wqT,
                                               unsigned short* __restrict__ Weff) {
    __shared__ __align__(16) unsigned short As[128 * 32];   // c-rows (wqT)
    __shared__ __align__(16) unsigned short Bs[128 * 32];   // o-rows (Wc)
    const int t = threadIdx.x;
    const int c0 = blockIdx.x * 128, o0 = blockIdx.y * 128, bz = blockIdx.z;
    const int lane = t & 63, wv = t >> 6, quad = lane >> 4, l15 = lane & 15;
    const int wmC = (wv & 1) * 64, wnO = (wv >> 1) * 64;

    const int srow = lane >> 2, scol = (lane & 3) * 8;
    unsigned short* Al0 = As + wv * 16 * 32;
    unsigned short* Al1 = Al0 + 64 * 32;
    unsigned short* Bl0 = Bs + wv * 16 * 32;
    unsigned short* Bl1 = Bl0 + 64 * 32;
    const unsigned short* Ag0 = wqT + (size_t)(c0 + wv * 16 + srow) * HID + scol;
    const unsigned short* Ag1 = Ag0 + 64 * HID;
    const unsigned short* Bg0 = Wc + ((size_t)bz * 256 + o0 + wv * 16 + srow) * HID + scol;
    const unsigned short* Bg1 = Bg0 + 64 * HID;

    v4f acc[4][4];
    #pragma unroll
    for (int i = 0; i < 4; i++)
        #pragma unroll
        for (int j = 0; j < 4; j++) acc[i][j] = (v4f)0.f;

    for (int kk = 0; kk < HID; kk += 32) {
        gld_lds16(Ag0 + kk, Al0);
        gld_lds16(Ag1 + kk, Al1);
        gld_lds16(Bg0 + kk, Bl0);
        gld_lds16(Bg1 + kk, Bl1);
        __syncthreads();
        v8s af[4], bfr[4];
        #pragma unroll
        for (int mi = 0; mi < 4; mi++) {
            union { v8s v; uint4 u; } rr;
            rr.u = *(const uint4*)(&As[(wmC + mi * 16 + l15) * 32 + quad * 8]);
            af[mi] = rr.v;
        }
        #pragma unroll
        for (int ni = 0; ni < 4; ni++) {
            union { v8s v; uint4 u; } rr;
            rr.u = *(const uint4*)(&Bs[(wnO + ni * 16 + l15) * 32 + quad * 8]);
            bfr[ni] = rr.v;
        }
        #pragma unroll
        for (int mi = 0; mi < 4; mi++)
            #pragma unroll
            for (int ni = 0; ni < 4; ni++)
                acc[mi][ni] = __builtin_amdgcn_mfma_f32_16x16x32_bf16(af[mi], bfr[ni], acc[mi][ni], 0, 0, 0);
        __syncthreads();
    }
    #pragma unroll
    for (int ni = 0; ni < 4; ni++) {
        const int o = o0 + wnO + ni * 16 + l15;
        #pragma unroll
        for (int mi = 0; mi < 4; mi++) {
            const int c = c0 + wmC + mi * 16 + quad * 4;
            union { unsigned short s[4]; uint2 u; } p;
            #pragma unroll
            for (int rr = 0; rr < 4; rr++) p.s[rr] = f2bf(acc[mi][ni][rr]);
            *(uint2*)(Weff + ((size_t)bz * 256 + o) * 256 + c) = p.u;
        }
    }
}

// ---------------- K6: y = Weff @ x + b_out, computed as C^T (M=n, N=o) --------------
__global__ __launch_bounds__(256) void k_y(const unsigned short* __restrict__ Weff,
                                           const unsigned short* __restrict__ xT,
                                           const float* __restrict__ b_out,
                                           float* __restrict__ y) {
    __shared__ __align__(16) unsigned short As[128 * 32];   // n-rows (xT)
    __shared__ __align__(16) unsigned short Bs[128 * 32];   // o-rows (Weff)
    const int t = threadIdx.x;
    const int o0 = blockIdx.x * 128;
    const int n0 = blockIdx.y * 128;
    const int bz = blockIdx.z;
    const int lane = t & 63, wv = t >> 6, quad = lane >> 4, l15 = lane & 15;
    const int wmN = (wv & 1) * 64, wnO = (wv >> 1) * 64;

    const int srow = lane >> 2, scol = (lane & 3) * 8;
    unsigned short* Al0 = As + wv * 16 * 32;
    unsigned short* Al1 = Al0 + 64 * 32;
    unsigned short* Bl0 = Bs + wv * 16 * 32;
    unsigned short* Bl1 = Bl0 + 64 * 32;
    const unsigned short* Ag0 = xT + ((size_t)bz * NSP + n0 + wv * 16 + srow) * CIN + scol;
    const unsigned short* Ag1 = Ag0 + 64 * CIN;
    const unsigned short* Bg0 = Weff + ((size_t)bz * 256 + o0 + wv * 16 + srow) * CIN + scol;
    const unsigned short* Bg1 = Bg0 + 64 * CIN;

    v4f acc[4][4];
    #pragma unroll
    for (int i = 0; i < 4; i++)
        #pragma unroll
        for (int j = 0; j < 4; j++) acc[i][j] = (v4f)0.f;

    for (int kk = 0; kk < CIN; kk += 32) {
        gld_lds16(Ag0 + kk, Al0);
        gld_lds16(Ag1 + kk, Al1);
        gld_lds16(Bg0 + kk, Bl0);
        gld_lds16(Bg1 + kk, Bl1);
        __syncthreads();
        v8s af[4], bfr[4];
        #pragma unroll
        for (int mi = 0; mi < 4; mi++) {
            union { v8s v; uint4 u; } rr;
            rr.u = *(const uint4*)(&As[(wmN + mi * 16 + l15) * 32 + quad * 8]);
            af[mi] = rr.v;
        }
        #pragma unroll
        for (int ni = 0; ni < 4; ni++) {
            union { v8s v; uint4 u; } rr;
            rr.u = *(const uint4*)(&Bs[(wnO + ni * 16 + l15) * 32 + quad * 8]);
            bfr[ni] = rr.v;
        }
        #pragma unroll
        for (int mi = 0; mi < 4; mi++)
            #pragma unroll
            for (int ni = 0; ni < 4; ni++)
                acc[mi][ni] = __builtin_amdgcn_mfma_f32_16x16x32_bf16(af[mi], bfr[ni], acc[mi][ni], 0, 0, 0);
        __syncthreads();
    }
    #pragma unroll
    for (int ni = 0; ni < 4; ni++) {
        const int o = o0 + wnO + ni * 16 + l15;
        const float bias = b_out[o];
        #pragma unroll
        for (int mi = 0; mi < 4; mi++) {
            const int n = n0 + wmN + mi * 16 + quad * 4;
            v4f v = acc[mi][ni];
            v[0] += bias; v[1] += bias; v[2] += bias; v[3] += bias;
            *(v4f*)(y + ((size_t)bz * 256 + o) * NSP + n) = v;
        }
    }
}

extern "C" void kernel_launch(void* const* d_in, const int* in_sizes, int n_in,
                              void* d_out, int out_size, void* d_ws, size_t ws_size,
                              hipStream_t stream) {
    (void)in_sizes; (void)n_in; (void)out_size; (void)ws_size;
    const float* x     = (const float*)d_in[0];
    const float* w_qkv = (const float*)d_in[1];
    const float* w_out = (const float*)d_in[2];
    const float* b_out = (const float*)d_in[3];
    float* y = (float*)d_out;
    char* ws = (char*)d_ws;

    unsigned short* xT   = (unsigned short*)(ws);                 //  33,554,432 B
    unsigned short* xbf  = (unsigned short*)(ws + 33554432);      //  33,554,432 B
    unsigned short* expk = (unsigned short*)(ws + 67108864);      //  67,108,864 B
    float*          Sp   = (float*)(ws + 134217728);              //  33,554,432 B
    float*          zp   = (float*)(ws + 167772160);              //   8,388,608 B
    unsigned short* Sred = (unsigned short*)(ws + 176160768);     //   4,194,304 B
    unsigned short* Wc   = (unsigned short*)(ws + 180355072);     //   4,194,304 B
    unsigned short* Weff = (unsigned short*)(ws + 184549376);     //   2,097,152 B
    unsigned short* wbf  = (unsigned short*)(ws + 186646528);     //     786,432 B
    unsigned short* wqT  = (unsigned short*)(ws + 187432960);     //     524,288 B

    k_w    <<<dim3(224),        256, 0, stream>>>(w_qkv, wbf, wqT);
    k_prep <<<dim3(64, 4, 16),  256, 0, stream>>>(x, xbf, xT);
    k_k    <<<dim3(2048),       256, 0, stream>>>(wbf, xT, expk, zp);
    k_S    <<<dim3(512),        256, 0, stream>>>(expk, xbf, Sp);
    k_sred <<<dim3(2048),       256, 0, stream>>>(Sp, Sred);
    k_redwc<<<dim3(64),         256, 0, stream>>>(Sred, zp, wbf, w_out, Wc);
    k_chain<<<dim3(2, 2, 16),   256, 0, stream>>>(Wc, wqT, Weff);
    k_y    <<<dim3(2, 32, 16),  256, 0, stream>>>(Weff, xT, b_out, y);
}